// Round 3
// baseline (270.188 us; speedup 1.0000x reference)
//
#include <hip/hip_runtime.h>

typedef unsigned short ushort_t;
typedef unsigned int uint_t;
typedef __attribute__((ext_vector_type(8))) short bf16x8;
typedef __attribute__((ext_vector_type(4))) float f32x4;

#define NMAT 16
#define MSZ 16384  // 128*128
#define NTAB 126   // table entries: levels 1..6, off(L) = (1<<L)-2

__device__ __forceinline__ ushort_t f32_bf16(float f) {
  uint_t u = __builtin_bit_cast(uint_t, f);
  u += 0x7FFFu + ((u >> 16) & 1u);  // round-to-nearest-even
  return (ushort_t)(u >> 16);
}

__device__ __forceinline__ float bf16_f32(ushort_t b) {
  uint_t u = ((uint_t)b) << 16;
  return __builtin_bit_cast(float, u);
}

// XOR swizzle on 16B granules: row r, elem k of a 128x128 bf16 tile.
__device__ __forceinline__ int swz(int r, int k) {
  return r * 128 + (((k >> 3) ^ (r & 7)) << 3) + (k & 7);
}

// level-L chunks live at [off(L) .. off(L)+2^L), off(L) = 2^L - 2
__device__ __forceinline__ int tab_off(int L) { return (1 << L) - 2; }

__device__ __forceinline__ void mm_zero(f32x4 (&acc)[4][4]) {
#pragma unroll
  for (int rt = 0; rt < 4; rt++)
#pragma unroll
    for (int ct = 0; ct < 4; ct++) {
      f32x4 z = {0.f, 0.f, 0.f, 0.f};
      acc[rt][ct] = z;
    }
}

// D[r][c] = sum_k U[r][k]*V[c][k] = U * V^T (U,V swizzled LDS tiles).
__device__ __forceinline__ void mm_frag(const ushort_t* U, const ushort_t* V,
                                        int r0, int c0, int quad, int l16,
                                        f32x4 (&acc)[4][4]) {
  mm_zero(acc);
#pragma unroll
  for (int kt = 0; kt < 4; kt++) {
    int k = kt * 32 + quad * 8;
    bf16x8 a[4], b[4];
#pragma unroll
    for (int rt = 0; rt < 4; rt++) a[rt] = *(const bf16x8*)(&U[swz(r0 + rt * 16 + l16, k)]);
#pragma unroll
    for (int ct = 0; ct < 4; ct++) b[ct] = *(const bf16x8*)(&V[swz(c0 + ct * 16 + l16, k)]);
#pragma unroll
    for (int rt = 0; rt < 4; rt++)
#pragma unroll
      for (int ct = 0; ct < 4; ct++)
        acc[rt][ct] = __builtin_amdgcn_mfma_f32_16x16x32_bf16(a[rt], b[ct], acc[rt][ct], 0, 0, 0);
  }
}

// U rows from global gU, V rows from global gV: D = U * V^T
__device__ __forceinline__ void mm_gg(const ushort_t* gU, const ushort_t* gV,
                                      int r0, int c0, int quad, int l16,
                                      f32x4 (&acc)[4][4]) {
  mm_zero(acc);
#pragma unroll
  for (int kt = 0; kt < 4; kt++) {
    int k = kt * 32 + quad * 8;
    bf16x8 a[4], b[4];
#pragma unroll
    for (int rt = 0; rt < 4; rt++) a[rt] = *(const bf16x8*)(gU + (r0 + rt * 16 + l16) * 128 + k);
#pragma unroll
    for (int ct = 0; ct < 4; ct++) b[ct] = *(const bf16x8*)(gV + (c0 + ct * 16 + l16) * 128 + k);
#pragma unroll
    for (int rt = 0; rt < 4; rt++)
#pragma unroll
      for (int ct = 0; ct < 4; ct++)
        acc[rt][ct] = __builtin_amdgcn_mfma_f32_16x16x32_bf16(a[rt], b[ct], acc[rt][ct], 0, 0, 0);
  }
}

// U rows from global, V rows from swizzled LDS
__device__ __forceinline__ void mm_gl(const ushort_t* gU, const ushort_t* lV,
                                      int r0, int c0, int quad, int l16,
                                      f32x4 (&acc)[4][4]) {
  mm_zero(acc);
#pragma unroll
  for (int kt = 0; kt < 4; kt++) {
    int k = kt * 32 + quad * 8;
    bf16x8 a[4], b[4];
#pragma unroll
    for (int rt = 0; rt < 4; rt++) a[rt] = *(const bf16x8*)(gU + (r0 + rt * 16 + l16) * 128 + k);
#pragma unroll
    for (int ct = 0; ct < 4; ct++) b[ct] = *(const bf16x8*)(&lV[swz(c0 + ct * 16 + l16, k)]);
#pragma unroll
    for (int rt = 0; rt < 4; rt++)
#pragma unroll
      for (int ct = 0; ct < 4; ct++)
        acc[rt][ct] = __builtin_amdgcn_mfma_f32_16x16x32_bf16(a[rt], b[ct], acc[rt][ct], 0, 0, 0);
  }
}

// U rows from swizzled LDS, V rows from global
__device__ __forceinline__ void mm_lg(const ushort_t* lU, const ushort_t* gV,
                                      int r0, int c0, int quad, int l16,
                                      f32x4 (&acc)[4][4]) {
  mm_zero(acc);
#pragma unroll
  for (int kt = 0; kt < 4; kt++) {
    int k = kt * 32 + quad * 8;
    bf16x8 a[4], b[4];
#pragma unroll
    for (int rt = 0; rt < 4; rt++) a[rt] = *(const bf16x8*)(&lU[swz(r0 + rt * 16 + l16, k)]);
#pragma unroll
    for (int ct = 0; ct < 4; ct++) b[ct] = *(const bf16x8*)(gV + (c0 + ct * 16 + l16) * 128 + k);
#pragma unroll
    for (int rt = 0; rt < 4; rt++)
#pragma unroll
      for (int ct = 0; ct < 4; ct++)
        acc[rt][ct] = __builtin_amdgcn_mfma_f32_16x16x32_bf16(a[rt], b[ct], acc[rt][ct], 0, 0, 0);
  }
}

// packed global store of D^T row-major: dst[dc][dr..dr+3] <- acc
__device__ __forceinline__ void store_pk_global(ushort_t* dst, const f32x4 (&acc)[4][4],
                                                int r0, int c0, int quad, int l16) {
#pragma unroll
  for (int rt = 0; rt < 4; rt++)
#pragma unroll
    for (int ct = 0; ct < 4; ct++) {
      int dr = r0 + rt * 16 + quad * 4, dc = c0 + ct * 16 + l16;
      uint2 pk;
      pk.x = (uint_t)f32_bf16(acc[rt][ct][0]) | ((uint_t)f32_bf16(acc[rt][ct][1]) << 16);
      pk.y = (uint_t)f32_bf16(acc[rt][ct][2]) | ((uint_t)f32_bf16(acc[rt][ct][3]) << 16);
      *(uint2*)(dst + dc * 128 + dr) = pk;
    }
}

// store (scale*D + cdiag*I)^T into swizzled LDS, packed b64
__device__ __forceinline__ void store_T(ushort_t* dst, const f32x4 (&acc)[4][4],
                                        int r0, int c0, int quad, int l16,
                                        float scale, float cdiag) {
#pragma unroll
  for (int rt = 0; rt < 4; rt++)
#pragma unroll
    for (int ct = 0; ct < 4; ct++) {
      int dr = r0 + rt * 16 + quad * 4, dc = c0 + ct * 16 + l16;
      float v[4];
#pragma unroll
      for (int i = 0; i < 4; i++) {
        v[i] = scale * acc[rt][ct][i];
        if (dr + i == dc) v[i] += cdiag;
      }
      uint2 pk;
      pk.x = (uint_t)f32_bf16(v[0]) | ((uint_t)f32_bf16(v[1]) << 16);
      pk.y = (uint_t)f32_bf16(v[2]) | ((uint_t)f32_bf16(v[3]) << 16);
      *(uint2*)(&dst[swz(dc, dr)]) = pk;
    }
}

__device__ __forceinline__ void set_ident(ushort_t* dst, int t, float c) {
  ushort_t cb = f32_bf16(c);
  for (int i = 0; i < 64; i++) {
    int e = i * 256 + t;
    int r = e >> 7, k = e & 127;
    dst[swz(r, k)] = (r == k) ? cb : (ushort_t)0;
  }
}

// ---------------------------------------------------------------- expm part 1
// blocks 0..31: block = 2*kmat + which. X=(p-p^T)/8 (s=3). Y=X^2, Z=Y^2,
// Estrin: f(Y) = sum Z^i (c2i I + c2i+1 Y), Horner in Z. 6 serial matmuls.
// blocks 32..: fused steps_kernel rows (fills the idle CUs of this launch).
__global__ __launch_bounds__(256, 2) void expm1_kernel(
    const float* __restrict__ prim, ushort_t* __restrict__ wsCS,
    ushort_t* __restrict__ wsX, const int* __restrict__ pos,
    float* __restrict__ os, int N) {
  int bx = blockIdx.x;
  int t = threadIdx.x;
  if (bx >= 32) {  // ---- steps rows
    int i = bx - 32, j = t;
    int mi = pos[i] + 1, mj = pos[j] + 1;
    int di = 31 - __builtin_clz((unsigned)mi);
    int dj = 31 - __builtin_clz((unsigned)mj);
    int tt = di < dj ? di : dj;
    unsigned x = (unsigned)((mi >> (di - tt)) ^ (mj >> (dj - tt)));
    int cpl = tt - (x ? (32 - __builtin_clz(x)) : 0);
    os[i * N + j] = (float)(di + dj - 2 * cpl);
    return;
  }

  __shared__ ushort_t __align__(16) smem[2 * MSZ];  // 64 KB, two phases
  ushort_t* bufA = smem;            // X -> W (Horner accumulator)
  ushort_t* bufB = smem + MSZ;      // Y -> Z (in place)
  float* pf = (float*)smem;         // phase-1 f32 stage of p (64 KB)

  int kmat = bx >> 1, which = bx & 1;
  int wave = t >> 6, lane = t & 63;
  int quad = lane >> 4, l16 = lane & 15;
  int r0 = (wave >> 1) * 64, c0 = (wave & 1) * 64;
  const float* p = prim + kmat * MSZ;

  // phase 1: stage p coalesced into XOR-swizzled f32 LDS (conflict-free both ways)
  for (int i = 0; i < 64; i++) {
    int e = i * 256 + t;
    int r = e >> 7, c = e & 127;
    pf[r * 128 + (c ^ (r & 31))] = p[e];
  }
  __syncthreads();

  // X into registers: X[r][c] = (p[r][c] - p[c][r]) / 8
  ushort_t xr[64];
#pragma unroll
  for (int i = 0; i < 64; i++) {
    int e = i * 256 + t;
    int r = e >> 7, c = e & 127;
    float a = pf[r * 128 + (c ^ (r & 31))];
    float b = pf[c * 128 + (r ^ (c & 31))];
    xr[i] = f32_bf16((a - b) * 0.125f);
  }
  __syncthreads();
#pragma unroll
  for (int i = 0; i < 64; i++) {
    int e = i * 256 + t;
    int r = e >> 7, c = e & 127;
    bufA[swz(r, c)] = xr[i];
  }
  if (which == 0) {  // dump X bf16 for expm2 (coalesced)
    ushort_t* xd = wsX + (size_t)kmat * MSZ;
#pragma unroll
    for (int i = 0; i < 64; i++) xd[i * 256 + t] = xr[i];
  }
  __syncthreads();

  f32x4 acc[4][4];
  // Y = X^2 = -(X * X^T) -> bufB (symmetric)
  mm_frag(bufA, bufA, r0, c0, quad, l16, acc);
  __syncthreads();
  store_T(bufB, acc, r0, c0, quad, l16, -1.f, 0.f);
  __syncthreads();

  // cache Y addend fragments: yv[rt][ct] = Y[dc][dr..dr+3]
  uint2 yv[4][4];
#pragma unroll
  for (int rt = 0; rt < 4; rt++)
#pragma unroll
    for (int ct = 0; ct < 4; ct++) {
      int dr = r0 + rt * 16 + quad * 4, dc = c0 + ct * 16 + l16;
      yv[rt][ct] = *(const uint2*)(&bufB[swz(dc, dr)]);
    }

  // Z = Y^2 -> bufB in place
  mm_frag(bufB, bufB, r0, c0, quad, l16, acc);
  __syncthreads();
  store_T(bufB, acc, r0, c0, quad, l16, 1.f, 0.f);

  float coef[9];
  if (which == 0) {  // C: c_j = 1/(2j)!
    coef[0] = 1.f; coef[1] = 1.f / 2; coef[2] = 1.f / 24; coef[3] = 1.f / 720;
    coef[4] = 1.f / 40320; coef[5] = 1.f / 3628800.f; coef[6] = 1.f / 479001600.f;
    coef[7] = 1.f / 87178291200.f; coef[8] = 1.f / 20922789888000.f;
  } else {           // S: c_j = 1/(2j+1)!
    coef[0] = 1.f; coef[1] = 1.f / 6; coef[2] = 1.f / 120; coef[3] = 1.f / 5040;
    coef[4] = 1.f / 362880.f; coef[5] = 1.f / 39916800.f; coef[6] = 1.f / 6227020800.f;
    coef[7] = 1.f / 1307674368000.f; coef[8] = 1.f / 355687428096000.f;
  }

  // W = c8*I (bufA; X dead). Single barrier covers Z-store + ident-store.
  set_ident(bufA, t, coef[8]);
  __syncthreads();

#pragma unroll
  for (int k = 3; k >= 0; k--) {
    mm_frag(bufB, bufA, r0, c0, quad, l16, acc);  // Z * W
    __syncthreads();
    float cd = coef[2 * k], cy = coef[2 * k + 1];
#pragma unroll
    for (int rt = 0; rt < 4; rt++)
#pragma unroll
      for (int ct = 0; ct < 4; ct++) {
        int dr = r0 + rt * 16 + quad * 4, dc = c0 + ct * 16 + l16;
        uint2 yp = yv[rt][ct];
        float y[4] = {bf16_f32((ushort_t)(yp.x & 0xffff)), bf16_f32((ushort_t)(yp.x >> 16)),
                      bf16_f32((ushort_t)(yp.y & 0xffff)), bf16_f32((ushort_t)(yp.y >> 16))};
        float v[4];
#pragma unroll
        for (int i = 0; i < 4; i++) {
          v[i] = acc[rt][ct][i] + cy * y[i];
          if (dr + i == dc) v[i] += cd;
        }
        uint2 pk;
        pk.x = (uint_t)f32_bf16(v[0]) | ((uint_t)f32_bf16(v[1]) << 16);
        pk.y = (uint_t)f32_bf16(v[2]) | ((uint_t)f32_bf16(v[3]) << 16);
        *(uint2*)(&bufA[swz(dc, dr)]) = pk;
      }
    __syncthreads();
  }
  // emit row-major (unswizzled granule copy)
  ushort_t* dst = wsCS + (size_t)(which * NMAT + kmat) * MSZ;
  for (int i = 0; i < 8; i++) {
    int e = (i * 256 + t) * 8;
    int r = e >> 7, k = e & 127;
    *(uint4*)(dst + e) = *(const uint4*)(&bufA[swz(r, k)]);
  }
}

// ---------------------------------------------------------------- expm part 2
// Reads X (bf16, from expm1) + C,S. F = X*S; E = C+F, E^T = C-F; 3 squarings.
// Writes level-1 table entries TN (P row-major), TT (P^T row-major).
__global__ __launch_bounds__(256, 1) void expm2_kernel(
    const ushort_t* __restrict__ wsX, const ushort_t* __restrict__ wsCS,
    ushort_t* __restrict__ TN, ushort_t* __restrict__ TT) {
  __shared__ ushort_t __align__(16) bufA[MSZ];  // X -> EN/GN (row-major E)
  __shared__ ushort_t __align__(16) bufB[MSZ];  // S -> ET/GT (row-major E^T)
  int kmat = blockIdx.x;
  int t = threadIdx.x, wave = t >> 6, lane = t & 63;
  int quad = lane >> 4, l16 = lane & 15;
  int r0 = (wave >> 1) * 64, c0 = (wave & 1) * 64;
  const ushort_t* Xg = wsX + (size_t)kmat * MSZ;
  const ushort_t* Cg = wsCS + (size_t)kmat * MSZ;
  const ushort_t* Sg = wsCS + (size_t)(NMAT + kmat) * MSZ;

  for (int i = 0; i < 8; i++) {
    int e = (i * 256 + t) * 8;
    int r = e >> 7, k = e & 127;
    *(uint4*)(&bufA[swz(r, k)]) = *(const uint4*)(Xg + e);
    *(uint4*)(&bufB[swz(r, k)]) = *(const uint4*)(Sg + e);
  }
  __syncthreads();

  f32x4 acc[4][4];
  mm_frag(bufA, bufB, r0, c0, quad, l16, acc);  // F = X * S^T = X*S
  __syncthreads();
#pragma unroll
  for (int rt = 0; rt < 4; rt++)
#pragma unroll
    for (int ct = 0; ct < 4; ct++) {
      int dr = r0 + rt * 16 + quad * 4, dc = c0 + ct * 16 + l16;
      uint2 cp = *(const uint2*)(Cg + dc * 128 + dr);  // C[dc][dr..dr+3]
      float cf[4] = {bf16_f32((ushort_t)(cp.x & 0xffff)), bf16_f32((ushort_t)(cp.x >> 16)),
                     bf16_f32((ushort_t)(cp.y & 0xffff)), bf16_f32((ushort_t)(cp.y >> 16))};
      uint2 en, et;
      en.x = (uint_t)f32_bf16(cf[0] - acc[rt][ct][0]) | ((uint_t)f32_bf16(cf[1] - acc[rt][ct][1]) << 16);
      en.y = (uint_t)f32_bf16(cf[2] - acc[rt][ct][2]) | ((uint_t)f32_bf16(cf[3] - acc[rt][ct][3]) << 16);
      et.x = (uint_t)f32_bf16(cf[0] + acc[rt][ct][0]) | ((uint_t)f32_bf16(cf[1] + acc[rt][ct][1]) << 16);
      et.y = (uint_t)f32_bf16(cf[2] + acc[rt][ct][2]) | ((uint_t)f32_bf16(cf[3] + acc[rt][ct][3]) << 16);
      *(uint2*)(&bufA[swz(dc, dr)]) = en;
      *(uint2*)(&bufB[swz(dc, dr)]) = et;
    }
  __syncthreads();

#pragma unroll 1
  for (int sq = 0; sq < 3; sq++) {
    mm_frag(bufA, bufB, r0, c0, quad, l16, acc);  // G = E*E
    __syncthreads();
#pragma unroll
    for (int rt = 0; rt < 4; rt++)
#pragma unroll
      for (int ct = 0; ct < 4; ct++) {
        int dr = r0 + rt * 16 + quad * 4, dc = c0 + ct * 16 + l16;
        uint2 pk;
        pk.x = (uint_t)f32_bf16(acc[rt][ct][0]) | ((uint_t)f32_bf16(acc[rt][ct][1]) << 16);
        pk.y = (uint_t)f32_bf16(acc[rt][ct][2]) | ((uint_t)f32_bf16(acc[rt][ct][3]) << 16);
        *(uint2*)(&bufB[swz(dc, dr)]) = pk;  // G^T row-major
#pragma unroll
        for (int i = 0; i < 4; i++) bufA[swz(dr + i, dc)] = f32_bf16(acc[rt][ct][i]);  // G row-major
      }
    __syncthreads();
  }
  // emit TN (=P row-major), TT (=P^T row-major) -> table level 1 (off(1)=0)
  for (int i = 0; i < 8; i++) {
    int e = (i * 256 + t) * 8;
    int r = e >> 7, k = e & 127;
    *(uint4*)(TN + (size_t)kmat * MSZ + e) = *(const uint4*)(&bufA[swz(r, k)]);
    *(uint4*)(TT + (size_t)kmat * MSZ + e) = *(const uint4*)(&bufB[swz(r, k)]);
  }
}

// ---------------------------------------------------------------- table A
// Levels 2,3 chained in-block from level-1. Entry idx<4: level-2 c=idx
// (T2 = P[c>>1]*P[c&1]); idx>=4: level-3 c=idx-4 (T3 = P[c>>2]*P[(c>>1)&1]*P[c&1]).
// Intermediate M in LDS; final step computes BOTH orientations as two packed
// products: D1 = P^T*M^T = T^T -> packed-store -> TN (T row-major);
//           D2 = M*P = T -> packed-store -> TT (T^T row-major).
__global__ __launch_bounds__(256, 2) void tableA_kernel(ushort_t* __restrict__ TN,
                                                        ushort_t* __restrict__ TT) {
  __shared__ ushort_t __align__(16) Mb[MSZ];  // 32 KB
  int bx = blockIdx.x;
  int idx = bx >> 3, h = bx & 7;
  int t = threadIdx.x, wave = t >> 6, lane = t & 63;
  int quad = lane >> 4, l16 = lane & 15;
  int r0 = (wave >> 1) * 64, c0 = (wave & 1) * 64;

  int b0, bmid, blast, eO, nmid;
  if (idx < 4) {
    int c = idx;
    b0 = c >> 1; blast = c & 1; bmid = 0; nmid = 0; eO = 2 + c;
  } else {
    int c = idx - 4;
    b0 = c >> 2; bmid = (c >> 1) & 1; blast = c & 1; nmid = 1; eO = 6 + c;
  }

  // stage M = P[b0] (row-major TN level-1 -> swizzled LDS)
  {
    const ushort_t* src = TN + ((size_t)b0 * 8 + h) * MSZ;
#pragma unroll
    for (int i = 0; i < 8; i++) {
      int e = (i * 256 + t) * 8;
      int r = e >> 7, k = e & 127;
      *(uint4*)(&Mb[swz(r, k)]) = *(const uint4*)(src + e);
    }
  }
  __syncthreads();

  f32x4 acc[4][4];
  if (nmid) {  // M <- M * P[bmid]  (in place, barrier-separated)
    const ushort_t* Pt = TT + ((size_t)bmid * 8 + h) * MSZ;
    mm_gl(Pt, Mb, r0, c0, quad, l16, acc);  // (M*P)^T
    __syncthreads();
    store_T(Mb, acc, r0, c0, quad, l16, 1.f, 0.f);  // packed transpose-store -> M*P
    __syncthreads();
  }

  const ushort_t* Pt = TT + ((size_t)blast * 8 + h) * MSZ;
  ushort_t* oN = TN + ((size_t)eO * 8 + h) * MSZ;
  ushort_t* oT = TT + ((size_t)eO * 8 + h) * MSZ;
  // D1 = P^T * M^T = T^T -> TN (row-major T)
  mm_gl(Pt, Mb, r0, c0, quad, l16, acc);
  store_pk_global(oN, acc, r0, c0, quad, l16);
  // D2 = M * P = T -> TT (row-major T^T)
  mm_lg(Mb, Pt, r0, c0, quad, l16, acc);
  store_pk_global(oT, acc, r0, c0, quad, l16);
}

// ---------------------------------------------------------------- table B
// Levels 4,5,6 single-product from levels 2,3 (no LDS, packed dual stores).
// idx<16: L4 c=idx: eA=2+(c>>2), eB=2+(c&3), eO=14+c
// idx<48: L5 c=idx-16: eA=2+(c>>3), eB=6+(c&7), eO=30+c
// else  : L6 c=idx-48: eA=6+(c>>3), eB=6+(c&7), eO=62+c
// D1 = TB^T*TA^T = T^T -> TN ; D2 = TA*TB = T -> TT.
__global__ __launch_bounds__(256) void tableB_kernel(ushort_t* __restrict__ TN,
                                                     ushort_t* __restrict__ TT) {
  int bx = blockIdx.x;
  int idx = bx >> 3, h = bx & 7;
  int t = threadIdx.x, wave = t >> 6, lane = t & 63;
  int quad = lane >> 4, l16 = lane & 15;
  int r0 = (wave >> 1) * 64, c0 = (wave & 1) * 64;

  int eA, eB, eO;
  if (idx < 16) {
    int c = idx;      eA = 2 + (c >> 2); eB = 2 + (c & 3); eO = 14 + c;
  } else if (idx < 48) {
    int c = idx - 16; eA = 2 + (c >> 3); eB = 6 + (c & 7); eO = 30 + c;
  } else {
    int c = idx - 48; eA = 6 + (c >> 3); eB = 6 + (c & 7); eO = 62 + c;
  }
  const ushort_t* An = TN + ((size_t)eA * 8 + h) * MSZ;  // TA rows
  const ushort_t* Bt = TT + ((size_t)eB * 8 + h) * MSZ;  // TB^T rows
  ushort_t* oN = TN + ((size_t)eO * 8 + h) * MSZ;
  ushort_t* oT = TT + ((size_t)eO * 8 + h) * MSZ;

  f32x4 acc[4][4];
  mm_gg(Bt, An, r0, c0, quad, l16, acc);  // TB^T * TA^T = T^T
  store_pk_global(oN, acc, r0, c0, quad, l16);
  mm_gg(An, Bt, r0, c0, quad, l16, acc);  // TA * TB = T
  store_pk_global(oT, acc, r0, c0, quad, l16);
}

// ---------------------------------------------------------------- maps (v5)
// Level-6 table => every chain is <= 1 matmul, zero LDS, zero barriers.
__global__ __launch_bounds__(256) void maps_kernel(
    const ushort_t* __restrict__ TN, const ushort_t* __restrict__ TT,
    const int* __restrict__ positions, float* __restrict__ out) {
  int bx = blockIdx.x;
  int n = bx >> 3, h = bx & 7;
  int t = threadIdx.x, wave = t >> 6, lane = t & 63;
  int quad = lane >> 4, l16 = lane & 15;
  int m = positions[n] + 1;
  int depth = 31 - __builtin_clz((unsigned)m);
  float* ob = out + (size_t)(n * 8 + h) * MSZ;

  if (depth == 0) {
    for (int i = 0; i < 64; i++) {
      int e = i * 256 + t;
      int r = e >> 7, k = e & 127;
      ob[e] = (r == k) ? 1.0f : 0.0f;
    }
    return;
  }
  if (depth <= 6) {  // whole path is one table entry: bf16 -> f32 copy
    int c = m & ((1 << depth) - 1);
    const ushort_t* src = TN + ((size_t)(tab_off(depth) + c) * 8 + h) * MSZ;
    for (int i = 0; i < 8; i++) {
      int e = (i * 256 + t) * 8;
      bf16x8 v = *(const bf16x8*)(src + e);
      f32x4 lo = {bf16_f32((ushort_t)v[0]), bf16_f32((ushort_t)v[1]),
                  bf16_f32((ushort_t)v[2]), bf16_f32((ushort_t)v[3])};
      f32x4 hi = {bf16_f32((ushort_t)v[4]), bf16_f32((ushort_t)v[5]),
                  bf16_f32((ushort_t)v[6]), bf16_f32((ushort_t)v[7])};
      *(f32x4*)(ob + e) = lo;
      *(f32x4*)(ob + e + 4) = hi;
    }
    return;
  }

  int L0 = depth - 6;                        // prefix length 1..6
  int c0v = (m >> 6) & ((1 << L0) - 1);      // root-side chunk
  int suf = m & 63;                          // leaf-side 6 bits
  const ushort_t* U = TT + ((size_t)(62 + suf) * 8 + h) * MSZ;
  const ushort_t* V = TN + ((size_t)(tab_off(L0) + c0v) * 8 + h) * MSZ;

  int r0 = (wave >> 1) * 64, c0 = (wave & 1) * 64;
  f32x4 acc[4][4];
  mm_gg(U, V, r0, c0, quad, l16, acc);  // T6^T * M1^T = M^T
  // packed f32 store: acc[rt][ct] = M[dc][dr..dr+3]
#pragma unroll
  for (int rt = 0; rt < 4; rt++)
#pragma unroll
    for (int ct = 0; ct < 4; ct++) {
      int dr = r0 + rt * 16 + quad * 4;
      int dc = c0 + ct * 16 + l16;
      *(f32x4*)(ob + dc * 128 + dr) = acc[rt][ct];
    }
}

// ---------------------------------------------------------------- launch
extern "C" void kernel_launch(void* const* d_in, const int* in_sizes, int n_in,
                              void* d_out, int out_size, void* d_ws, size_t ws_size,
                              hipStream_t stream) {
  const float* prim = (const float*)d_in[0];
  const int* positions = (const int*)d_in[1];
  int N = in_sizes[1];  // 256
  float* out = (float*)d_out;

  // workspace: wsCS 32 | wsX 16 | TN 126*8 | TT 126*8  (bf16 128x128 mats)
  ushort_t* wsCS = (ushort_t*)d_ws;
  ushort_t* wsX = wsCS + (size_t)2 * NMAT * MSZ;
  ushort_t* TN = wsX + (size_t)NMAT * MSZ;
  ushort_t* TT = TN + (size_t)NTAB * 8 * MSZ;

  float* steps_out = out + (size_t)N * 8 * MSZ;
  expm1_kernel<<<32 + N, 256, 0, stream>>>(prim, wsCS, wsX, positions, steps_out, N);
  expm2_kernel<<<NMAT, 256, 0, stream>>>(wsX, wsCS, TN, TT);  // level 1
  tableA_kernel<<<96, 256, 0, stream>>>(TN, TT);              // levels 2,3
  tableB_kernel<<<896, 256, 0, stream>>>(TN, TT);             // levels 4,5,6
  maps_kernel<<<N * 8, 256, 0, stream>>>(TN, TT, positions, out);
}

// Round 4
// 249.456 us; speedup vs baseline: 1.0831x; 1.0831x over previous
//
#include <hip/hip_runtime.h>

typedef unsigned short ushort_t;
typedef unsigned int uint_t;
typedef __attribute__((ext_vector_type(8))) short bf16x8;
typedef __attribute__((ext_vector_type(4))) float f32x4;

#define NMAT 16
#define MSZ 16384  // 128*128
#define NTAB 30    // table entries: levels 1..4, off(L) = {0,2,6,14}

__device__ __forceinline__ ushort_t f32_bf16(float f) {
  uint_t u = __builtin_bit_cast(uint_t, f);
  u += 0x7FFFu + ((u >> 16) & 1u);  // round-to-nearest-even
  return (ushort_t)(u >> 16);
}

__device__ __forceinline__ float bf16_f32(ushort_t b) {
  uint_t u = ((uint_t)b) << 16;
  return __builtin_bit_cast(float, u);
}

// XOR swizzle on 16B granules: row r, elem k of a 128x128 bf16 tile.
__device__ __forceinline__ int swz(int r, int k) {
  return r * 128 + (((k >> 3) ^ (r & 7)) << 3) + (k & 7);
}

// level-L chunks live at [off(L) .. off(L)+2^L)
__device__ __forceinline__ int tab_off(int L) {
  return (L == 1) ? 0 : (L == 2) ? 2 : (L == 3) ? 6 : 14;  // 30 entries total
}

__device__ __forceinline__ void mm_zero(f32x4 (&acc)[4][4]) {
#pragma unroll
  for (int rt = 0; rt < 4; rt++)
#pragma unroll
    for (int ct = 0; ct < 4; ct++) {
      f32x4 z = {0.f, 0.f, 0.f, 0.f};
      acc[rt][ct] = z;
    }
}

// D[r][c] = sum_k U[r][k]*V[c][k] = U * V^T (U,V swizzled LDS tiles).
__device__ __forceinline__ void mm_frag(const ushort_t* U, const ushort_t* V,
                                        int r0, int c0, int quad, int l16,
                                        f32x4 (&acc)[4][4]) {
  mm_zero(acc);
#pragma unroll
  for (int kt = 0; kt < 4; kt++) {
    int k = kt * 32 + quad * 8;
    bf16x8 a[4], b[4];
#pragma unroll
    for (int rt = 0; rt < 4; rt++) a[rt] = *(const bf16x8*)(&U[swz(r0 + rt * 16 + l16, k)]);
#pragma unroll
    for (int ct = 0; ct < 4; ct++) b[ct] = *(const bf16x8*)(&V[swz(c0 + ct * 16 + l16, k)]);
#pragma unroll
    for (int rt = 0; rt < 4; rt++)
#pragma unroll
      for (int ct = 0; ct < 4; ct++)
        acc[rt][ct] = __builtin_amdgcn_mfma_f32_16x16x32_bf16(a[rt], b[ct], acc[rt][ct], 0, 0, 0);
  }
}

// U rows from global gU, V rows from global gV: D = U * V^T
__device__ __forceinline__ void mm_gg(const ushort_t* gU, const ushort_t* gV,
                                      int r0, int c0, int quad, int l16,
                                      f32x4 (&acc)[4][4]) {
  mm_zero(acc);
#pragma unroll
  for (int kt = 0; kt < 4; kt++) {
    int k = kt * 32 + quad * 8;
    bf16x8 a[4], b[4];
#pragma unroll
    for (int rt = 0; rt < 4; rt++) a[rt] = *(const bf16x8*)(gU + (r0 + rt * 16 + l16) * 128 + k);
#pragma unroll
    for (int ct = 0; ct < 4; ct++) b[ct] = *(const bf16x8*)(gV + (c0 + ct * 16 + l16) * 128 + k);
#pragma unroll
    for (int rt = 0; rt < 4; rt++)
#pragma unroll
      for (int ct = 0; ct < 4; ct++)
        acc[rt][ct] = __builtin_amdgcn_mfma_f32_16x16x32_bf16(a[rt], b[ct], acc[rt][ct], 0, 0, 0);
  }
}

// U rows from global, V rows from swizzled LDS
__device__ __forceinline__ void mm_gl(const ushort_t* gU, const ushort_t* lV,
                                      int r0, int c0, int quad, int l16,
                                      f32x4 (&acc)[4][4]) {
  mm_zero(acc);
#pragma unroll
  for (int kt = 0; kt < 4; kt++) {
    int k = kt * 32 + quad * 8;
    bf16x8 a[4], b[4];
#pragma unroll
    for (int rt = 0; rt < 4; rt++) a[rt] = *(const bf16x8*)(gU + (r0 + rt * 16 + l16) * 128 + k);
#pragma unroll
    for (int ct = 0; ct < 4; ct++) b[ct] = *(const bf16x8*)(&lV[swz(c0 + ct * 16 + l16, k)]);
#pragma unroll
    for (int rt = 0; rt < 4; rt++)
#pragma unroll
      for (int ct = 0; ct < 4; ct++)
        acc[rt][ct] = __builtin_amdgcn_mfma_f32_16x16x32_bf16(a[rt], b[ct], acc[rt][ct], 0, 0, 0);
  }
}

// packed global store of D^T row-major: dst[dc][dr..dr+3] <- acc
__device__ __forceinline__ void store_pk_global(ushort_t* dst, const f32x4 (&acc)[4][4],
                                                int r0, int c0, int quad, int l16) {
#pragma unroll
  for (int rt = 0; rt < 4; rt++)
#pragma unroll
    for (int ct = 0; ct < 4; ct++) {
      int dr = r0 + rt * 16 + quad * 4, dc = c0 + ct * 16 + l16;
      uint2 pk;
      pk.x = (uint_t)f32_bf16(acc[rt][ct][0]) | ((uint_t)f32_bf16(acc[rt][ct][1]) << 16);
      pk.y = (uint_t)f32_bf16(acc[rt][ct][2]) | ((uint_t)f32_bf16(acc[rt][ct][3]) << 16);
      *(uint2*)(dst + dc * 128 + dr) = pk;
    }
}

// store (scale*D + cdiag*I)^T into swizzled LDS, packed b64
__device__ __forceinline__ void store_T(ushort_t* dst, const f32x4 (&acc)[4][4],
                                        int r0, int c0, int quad, int l16,
                                        float scale, float cdiag) {
#pragma unroll
  for (int rt = 0; rt < 4; rt++)
#pragma unroll
    for (int ct = 0; ct < 4; ct++) {
      int dr = r0 + rt * 16 + quad * 4, dc = c0 + ct * 16 + l16;
      float v[4];
#pragma unroll
      for (int i = 0; i < 4; i++) {
        v[i] = scale * acc[rt][ct][i];
        if (dr + i == dc) v[i] += cdiag;
      }
      uint2 pk;
      pk.x = (uint_t)f32_bf16(v[0]) | ((uint_t)f32_bf16(v[1]) << 16);
      pk.y = (uint_t)f32_bf16(v[2]) | ((uint_t)f32_bf16(v[3]) << 16);
      *(uint2*)(&dst[swz(dc, dr)]) = pk;
    }
}

__device__ __forceinline__ void set_ident(ushort_t* dst, int t, float c) {
  ushort_t cb = f32_bf16(c);
  for (int i = 0; i < 64; i++) {
    int e = i * 256 + t;
    int r = e >> 7, k = e & 127;
    dst[swz(r, k)] = (r == k) ? cb : (ushort_t)0;
  }
}

// ---------------------------------------------------------------- expm part 1
// block = 2*kmat + which. X=(p-p^T)/8 (s=3 scaling). Y=X^2 symmetric. Z=Y^2.
// Estrin: f(Y) = sum_{i=0..4} Z^i (c_{2i} I + c_{2i+1} Y), Horner in Z.
// Serial matmuls: Y + Z + 4 = 6. All iterates poly(Y): symmetric, commute.
__global__ __launch_bounds__(256, 1) void expm1_kernel(const float* __restrict__ prim,
                                                       ushort_t* __restrict__ wsCS) {
  __shared__ ushort_t __align__(16) bufA[MSZ];  // X -> W (Horner accumulator)
  __shared__ ushort_t __align__(16) bufB[MSZ];  // Y -> Z (in place)
  int kmat = blockIdx.x >> 1, which = blockIdx.x & 1;
  int t = threadIdx.x, wave = t >> 6, lane = t & 63;
  int quad = lane >> 4, l16 = lane & 15;
  int r0 = (wave >> 1) * 64, c0 = (wave & 1) * 64;
  const float* p = prim + kmat * MSZ;

  // stage X -> bufA
  for (int i = 0; i < 64; i++) {
    int e = i * 256 + t;
    int r = e >> 7, c = e & 127;
    bufA[swz(r, c)] = f32_bf16((p[r * 128 + c] - p[c * 128 + r]) * 0.125f);
  }
  __syncthreads();

  f32x4 acc[4][4];
  // Y = X^2 = -(X * X^T) -> bufB (symmetric)
  mm_frag(bufA, bufA, r0, c0, quad, l16, acc);
  __syncthreads();
  store_T(bufB, acc, r0, c0, quad, l16, -1.f, 0.f);
  __syncthreads();

  // cache Y addend fragments in registers: yv[rt][ct] = Y[dc][dr..dr+3]
  uint2 yv[4][4];
#pragma unroll
  for (int rt = 0; rt < 4; rt++)
#pragma unroll
    for (int ct = 0; ct < 4; ct++) {
      int dr = r0 + rt * 16 + quad * 4, dc = c0 + ct * 16 + l16;
      yv[rt][ct] = *(const uint2*)(&bufB[swz(dc, dr)]);
    }

  // Z = Y^2 -> bufB in place (all reads drained at the barrier before store)
  mm_frag(bufB, bufB, r0, c0, quad, l16, acc);
  __syncthreads();
  store_T(bufB, acc, r0, c0, quad, l16, 1.f, 0.f);

  float coef[9];
  if (which == 0) {  // C: c_j = 1/(2j)!
    coef[0] = 1.f; coef[1] = 1.f / 2; coef[2] = 1.f / 24; coef[3] = 1.f / 720;
    coef[4] = 1.f / 40320; coef[5] = 1.f / 3628800.f; coef[6] = 1.f / 479001600.f;
    coef[7] = 1.f / 87178291200.f; coef[8] = 1.f / 20922789888000.f;
  } else {           // S: c_j = 1/(2j+1)!
    coef[0] = 1.f; coef[1] = 1.f / 6; coef[2] = 1.f / 120; coef[3] = 1.f / 5040;
    coef[4] = 1.f / 362880.f; coef[5] = 1.f / 39916800.f; coef[6] = 1.f / 6227020800.f;
    coef[7] = 1.f / 1307674368000.f; coef[8] = 1.f / 355687428096000.f;
  }

  // W = c8*I (bufA; X is dead). Single barrier covers Z-store + ident-store.
  set_ident(bufA, t, coef[8]);
  __syncthreads();

#pragma unroll
  for (int k = 3; k >= 0; k--) {
    mm_frag(bufB, bufA, r0, c0, quad, l16, acc);  // Z * W
    __syncthreads();
    float cd = coef[2 * k], cy = coef[2 * k + 1];
#pragma unroll
    for (int rt = 0; rt < 4; rt++)
#pragma unroll
      for (int ct = 0; ct < 4; ct++) {
        int dr = r0 + rt * 16 + quad * 4, dc = c0 + ct * 16 + l16;
        uint2 yp = yv[rt][ct];
        float y[4] = {bf16_f32((ushort_t)(yp.x & 0xffff)), bf16_f32((ushort_t)(yp.x >> 16)),
                      bf16_f32((ushort_t)(yp.y & 0xffff)), bf16_f32((ushort_t)(yp.y >> 16))};
        float v[4];
#pragma unroll
        for (int i = 0; i < 4; i++) {
          v[i] = acc[rt][ct][i] + cy * y[i];
          if (dr + i == dc) v[i] += cd;
        }
        uint2 pk;
        pk.x = (uint_t)f32_bf16(v[0]) | ((uint_t)f32_bf16(v[1]) << 16);
        pk.y = (uint_t)f32_bf16(v[2]) | ((uint_t)f32_bf16(v[3]) << 16);
        *(uint2*)(&bufA[swz(dc, dr)]) = pk;
      }
    __syncthreads();
  }
  // emit row-major (unswizzled granule copy)
  ushort_t* dst = wsCS + (size_t)(which * NMAT + kmat) * MSZ;
  for (int i = 0; i < 8; i++) {
    int e = (i * 256 + t) * 8;
    int r = e >> 7, k = e & 127;
    *(uint4*)(dst + e) = *(const uint4*)(&bufA[swz(r, k)]);
  }
}

// ---------------------------------------------------------------- expm part 2
// Writes level-1 table entries: TN[b*8+h] = P row-major, TT[b*8+h] = P^T row-major.
__global__ __launch_bounds__(256, 1) void expm2_kernel(
    const float* __restrict__ prim, const ushort_t* __restrict__ wsCS,
    ushort_t* __restrict__ TN, ushort_t* __restrict__ TT) {
  __shared__ ushort_t __align__(16) bufA[MSZ];  // X -> EN/GN (row-major E)
  __shared__ ushort_t __align__(16) bufB[MSZ];  // S -> ET/GT (row-major E^T)
  int kmat = blockIdx.x;
  int t = threadIdx.x, wave = t >> 6, lane = t & 63;
  int quad = lane >> 4, l16 = lane & 15;
  int r0 = (wave >> 1) * 64, c0 = (wave & 1) * 64;
  const float* p = prim + kmat * MSZ;
  const ushort_t* Cg = wsCS + (size_t)kmat * MSZ;
  const ushort_t* Sg = wsCS + (size_t)(NMAT + kmat) * MSZ;

  for (int i = 0; i < 64; i++) {
    int e = i * 256 + t;
    int r = e >> 7, c = e & 127;
    bufA[swz(r, c)] = f32_bf16((p[r * 128 + c] - p[c * 128 + r]) * 0.125f);
  }
  for (int i = 0; i < 8; i++) {
    int e = (i * 256 + t) * 8;
    int r = e >> 7, k = e & 127;
    *(uint4*)(&bufB[swz(r, k)]) = *(const uint4*)(Sg + e);
  }
  __syncthreads();

  f32x4 acc[4][4];
  mm_frag(bufA, bufB, r0, c0, quad, l16, acc);  // F = X * S^T = X*S
  __syncthreads();
#pragma unroll
  for (int rt = 0; rt < 4; rt++)
#pragma unroll
    for (int ct = 0; ct < 4; ct++) {
      int dr = r0 + rt * 16 + quad * 4, dc = c0 + ct * 16 + l16;
      uint2 cp = *(const uint2*)(Cg + dc * 128 + dr);  // C[dc][dr..dr+3]
      float cf[4] = {bf16_f32((ushort_t)(cp.x & 0xffff)), bf16_f32((ushort_t)(cp.x >> 16)),
                     bf16_f32((ushort_t)(cp.y & 0xffff)), bf16_f32((ushort_t)(cp.y >> 16))};
      uint2 en, et;
      en.x = (uint_t)f32_bf16(cf[0] - acc[rt][ct][0]) | ((uint_t)f32_bf16(cf[1] - acc[rt][ct][1]) << 16);
      en.y = (uint_t)f32_bf16(cf[2] - acc[rt][ct][2]) | ((uint_t)f32_bf16(cf[3] - acc[rt][ct][3]) << 16);
      et.x = (uint_t)f32_bf16(cf[0] + acc[rt][ct][0]) | ((uint_t)f32_bf16(cf[1] + acc[rt][ct][1]) << 16);
      et.y = (uint_t)f32_bf16(cf[2] + acc[rt][ct][2]) | ((uint_t)f32_bf16(cf[3] + acc[rt][ct][3]) << 16);
      *(uint2*)(&bufA[swz(dc, dr)]) = en;
      *(uint2*)(&bufB[swz(dc, dr)]) = et;
    }
  __syncthreads();

#pragma unroll 1
  for (int sq = 0; sq < 3; sq++) {
    mm_frag(bufA, bufB, r0, c0, quad, l16, acc);  // G = E*E
    __syncthreads();
#pragma unroll
    for (int rt = 0; rt < 4; rt++)
#pragma unroll
      for (int ct = 0; ct < 4; ct++) {
        int dr = r0 + rt * 16 + quad * 4, dc = c0 + ct * 16 + l16;
        uint2 pk;
        pk.x = (uint_t)f32_bf16(acc[rt][ct][0]) | ((uint_t)f32_bf16(acc[rt][ct][1]) << 16);
        pk.y = (uint_t)f32_bf16(acc[rt][ct][2]) | ((uint_t)f32_bf16(acc[rt][ct][3]) << 16);
        *(uint2*)(&bufB[swz(dc, dr)]) = pk;  // G^T row-major
#pragma unroll
        for (int i = 0; i < 4; i++) bufA[swz(dr + i, dc)] = f32_bf16(acc[rt][ct][i]);  // G row-major
      }
    __syncthreads();
  }
  // emit TN (=P row-major), TT (=P^T row-major) -> table level 1 (off(1)=0)
  for (int i = 0; i < 8; i++) {
    int e = (i * 256 + t) * 8;
    int r = e >> 7, k = e & 127;
    *(uint4*)(TN + (size_t)kmat * MSZ + e) = *(const uint4*)(&bufA[swz(r, k)]);
    *(uint4*)(TT + (size_t)kmat * MSZ + e) = *(const uint4*)(&bufB[swz(r, k)]);
  }
}

// ---------------------------------------------------------------- table A
// Level 2 (4 entries x 8 heads = 32 blocks): T2[c] = P[c>>1] * P[c&1].
// Both orientations as packed dual products:
//   TN2 = (P1^T * P0^T)^T-store = T2 row-major
//   TT2 = (P0 * P1)^T-store    = T2^T row-major
__global__ __launch_bounds__(256) void tableA_kernel(ushort_t* __restrict__ TN,
                                                     ushort_t* __restrict__ TT) {
  int bx = blockIdx.x;
  int c = bx >> 3, h = bx & 7;
  int t = threadIdx.x, wave = t >> 6, lane = t & 63;
  int quad = lane >> 4, l16 = lane & 15;
  int r0 = (wave >> 1) * 64, c0 = (wave & 1) * 64;

  const ushort_t* An = TN + ((size_t)(c >> 1) * 8 + h) * MSZ;  // P0 rows
  const ushort_t* Bt = TT + ((size_t)(c & 1) * 8 + h) * MSZ;   // P1^T rows
  ushort_t* oN = TN + ((size_t)(2 + c) * 8 + h) * MSZ;
  ushort_t* oT = TT + ((size_t)(2 + c) * 8 + h) * MSZ;

  f32x4 acc[4][4];
  mm_gg(Bt, An, r0, c0, quad, l16, acc);  // P1^T * P0^T = T2^T
  store_pk_global(oN, acc, r0, c0, quad, l16);
  mm_gg(An, Bt, r0, c0, quad, l16, acc);  // P0 * P1 = T2
  store_pk_global(oT, acc, r0, c0, quad, l16);
}

// ---------------------------------------------------------------- table B
// bx<64:  level 3, c = bx>>3: T3[c] = T2[c>>1] * P[c&1]. TN only (TT3 unused).
// bx>=64: level 4, c = (bx-64)>>3: T4[c] = T2[c>>2] * T2[c&3]. TN + TT.
__global__ __launch_bounds__(256) void tableB_kernel(ushort_t* __restrict__ TN,
                                                     ushort_t* __restrict__ TT) {
  int bx = blockIdx.x;
  int t = threadIdx.x, wave = t >> 6, lane = t & 63;
  int quad = lane >> 4, l16 = lane & 15;
  int r0 = (wave >> 1) * 64, c0 = (wave & 1) * 64;
  f32x4 acc[4][4];

  if (bx < 64) {
    int c = bx >> 3, h = bx & 7;
    const ushort_t* An = TN + ((size_t)(2 + (c >> 1)) * 8 + h) * MSZ;  // T2 rows
    const ushort_t* Bt = TT + ((size_t)(c & 1) * 8 + h) * MSZ;         // P^T rows
    ushort_t* oN = TN + ((size_t)(6 + c) * 8 + h) * MSZ;
    mm_gg(Bt, An, r0, c0, quad, l16, acc);  // P^T * T2^T = T3^T
    store_pk_global(oN, acc, r0, c0, quad, l16);
  } else {
    int c = (bx - 64) >> 3, h = (bx - 64) & 7;
    const ushort_t* An = TN + ((size_t)(2 + (c >> 2)) * 8 + h) * MSZ;  // T2a rows
    const ushort_t* Bt = TT + ((size_t)(2 + (c & 3)) * 8 + h) * MSZ;   // T2b^T rows
    ushort_t* oN = TN + ((size_t)(14 + c) * 8 + h) * MSZ;
    ushort_t* oT = TT + ((size_t)(14 + c) * 8 + h) * MSZ;
    mm_gg(Bt, An, r0, c0, quad, l16, acc);  // T2b^T * T2a^T = T4^T
    store_pk_global(oN, acc, r0, c0, quad, l16);
    mm_gg(An, Bt, r0, c0, quad, l16, acc);  // T2a * T2b = T4
    store_pk_global(oT, acc, r0, c0, quad, l16);
  }
}

// ---------------------------------------------------------------- steps
__global__ void steps_kernel(const int* __restrict__ pos, float* __restrict__ os, int N) {
  int i = blockIdx.x, j = threadIdx.x;
  int mi = pos[i] + 1, mj = pos[j] + 1;
  int di = 31 - __builtin_clz((unsigned)mi);
  int dj = 31 - __builtin_clz((unsigned)mj);
  int tt = di < dj ? di : dj;
  unsigned x = (unsigned)((mi >> (di - tt)) ^ (mj >> (dj - tt)));
  int cpl = tt - (x ? (32 - __builtin_clz(x)) : 0);
  os[i * N + j] = (float)(di + dj - 2 * cpl);
}

// ---------------------------------------------------------------- maps (v6)
// depth = L0 + 4*(K-1), L0 in 1..4. K-1 matmuls, no initial LDS stage:
//   step 1 (all-global): acc = T4[c1]^T * M0^T  (M0 = TN[L0 prefix])
//   K==3: packed writeback M1 -> LDS (32 KB), one barrier,
//         acc = T4[c2]^T * M1^T  (A global, B LDS)
// Final acc = M^T fragments = M[dc][dr..+3] -> packed f32x4 rows.
// K==2 (5.9%): zero LDS, zero barriers. K==3 (93.7%): one barrier.
// h = bx&7 == XCD id -> per-head table slice (~1 MB) stays L2-resident.
__global__ __launch_bounds__(256, 4) void maps_kernel(
    const ushort_t* __restrict__ TN, const ushort_t* __restrict__ TT,
    const int* __restrict__ positions, float* __restrict__ out) {
  __shared__ ushort_t __align__(16) Mb[MSZ];  // 32 KB
  int bx = blockIdx.x;
  int n = bx >> 3, h = bx & 7;
  int t = threadIdx.x, wave = t >> 6, lane = t & 63;
  int quad = lane >> 4, l16 = lane & 15;
  int m = positions[n] + 1;
  int depth = 31 - __builtin_clz((unsigned)m);
  float* ob = out + (size_t)(n * 8 + h) * MSZ;

  if (depth == 0) {
    for (int i = 0; i < 64; i++) {
      int e = i * 256 + t;
      int r = e >> 7, k = e & 127;
      ob[e] = (r == k) ? 1.0f : 0.0f;
    }
    return;
  }
  if (depth <= 4) {  // whole path is one table entry: bf16 -> f32 copy
    int c = m & ((1 << depth) - 1);
    const ushort_t* src = TN + ((size_t)(tab_off(depth) + c) * 8 + h) * MSZ;
    for (int i = 0; i < 8; i++) {
      int e = (i * 256 + t) * 8;
      bf16x8 v = *(const bf16x8*)(src + e);
      f32x4 lo = {bf16_f32((ushort_t)v[0]), bf16_f32((ushort_t)v[1]),
                  bf16_f32((ushort_t)v[2]), bf16_f32((ushort_t)v[3])};
      f32x4 hi = {bf16_f32((ushort_t)v[4]), bf16_f32((ushort_t)v[5]),
                  bf16_f32((ushort_t)v[6]), bf16_f32((ushort_t)v[7])};
      *(f32x4*)(ob + e) = lo;
      *(f32x4*)(ob + e + 4) = hi;
    }
    return;
  }

  int K = (depth + 3) >> 2;                       // 2 or 3 chunks
  int L0 = depth - 4 * (K - 1);                   // root chunk length 1..4
  int pre = (m >> (4 * (K - 1))) & ((1 << L0) - 1);
  int r0 = (wave >> 1) * 64, c0 = (wave & 1) * 64;
  f32x4 acc[4][4];

  // step 1: M1^T = T4[c1]^T * M0^T  (both operands straight from L2-hot tables)
  int c1 = (m >> (4 * (K - 2))) & 15;
  mm_gg(TT + ((size_t)(14 + c1) * 8 + h) * MSZ,
        TN + ((size_t)(tab_off(L0) + pre) * 8 + h) * MSZ,
        r0, c0, quad, l16, acc);

  if (K == 3) {
    store_T(Mb, acc, r0, c0, quad, l16, 1.f, 0.f);  // Mb = M1 row-major (swz)
    __syncthreads();
    int c2 = m & 15;
    mm_gl(TT + ((size_t)(14 + c2) * 8 + h) * MSZ, Mb, r0, c0, quad, l16, acc);
  }

  // packed f32 store: acc[rt][ct] = M[dc][dr..dr+3]
#pragma unroll
  for (int rt = 0; rt < 4; rt++)
#pragma unroll
    for (int ct = 0; ct < 4; ct++) {
      int dr = r0 + rt * 16 + quad * 4;
      int dc = c0 + ct * 16 + l16;
      *(f32x4*)(ob + dc * 128 + dr) = acc[rt][ct];
    }
}

// ---------------------------------------------------------------- launch
extern "C" void kernel_launch(void* const* d_in, const int* in_sizes, int n_in,
                              void* d_out, int out_size, void* d_ws, size_t ws_size,
                              hipStream_t stream) {
  const float* prim = (const float*)d_in[0];
  const int* positions = (const int*)d_in[1];
  int N = in_sizes[1];  // 256
  float* out = (float*)d_out;

  // workspace: wsCS 32 mats | TN 30*8 mats | TT 30*8 mats  => 16 MB total
  ushort_t* wsCS = (ushort_t*)d_ws;
  ushort_t* TN = wsCS + (size_t)2 * NMAT * MSZ;
  ushort_t* TT = TN + (size_t)NTAB * 8 * MSZ;

  steps_kernel<<<N, N, 0, stream>>>(positions, out + (size_t)N * 8 * MSZ, N);
  expm1_kernel<<<2 * NMAT, 256, 0, stream>>>(prim, wsCS);
  expm2_kernel<<<NMAT, 256, 0, stream>>>(prim, wsCS, TN, TT);  // level 1
  tableA_kernel<<<32, 256, 0, stream>>>(TN, TT);               // level 2
  tableB_kernel<<<192, 256, 0, stream>>>(TN, TT);              // levels 3,4
  maps_kernel<<<N * 8, 256, 0, stream>>>(TN, TT, positions, out);
}

// Round 5
// 235.210 us; speedup vs baseline: 1.1487x; 1.0606x over previous
//
#include <hip/hip_runtime.h>

typedef unsigned short ushort_t;
typedef unsigned int uint_t;
typedef __attribute__((ext_vector_type(8))) short bf16x8;
typedef __attribute__((ext_vector_type(4))) float f32x4;

#define NMAT 16
#define MSZ 16384  // 128*128
#define NTAB 30    // table entries: levels 1..4, off(L) = {0,2,6,14}

__device__ __forceinline__ ushort_t f32_bf16(float f) {
  uint_t u = __builtin_bit_cast(uint_t, f);
  u += 0x7FFFu + ((u >> 16) & 1u);  // round-to-nearest-even
  return (ushort_t)(u >> 16);
}

__device__ __forceinline__ float bf16_f32(ushort_t b) {
  uint_t u = ((uint_t)b) << 16;
  return __builtin_bit_cast(float, u);
}

// XOR swizzle on 16B granules: row r, elem k of a 128x128 bf16 tile.
__device__ __forceinline__ int swz(int r, int k) {
  return r * 128 + (((k >> 3) ^ (r & 7)) << 3) + (k & 7);
}

// level-L chunks live at [off(L) .. off(L)+2^L)
__device__ __forceinline__ int tab_off(int L) {
  return (L == 1) ? 0 : (L == 2) ? 2 : (L == 3) ? 6 : 14;  // 30 entries total
}

// D[r][c] = sum_k U[r][k]*V[c][k] = U * V^T (U,V swizzled LDS tiles).
__device__ __forceinline__ void mm_frag(const ushort_t* U, const ushort_t* V,
                                        int r0, int c0, int quad, int l16,
                                        f32x4 (&acc)[4][4]) {
#pragma unroll
  for (int rt = 0; rt < 4; rt++)
#pragma unroll
    for (int ct = 0; ct < 4; ct++) {
      f32x4 z = {0.f, 0.f, 0.f, 0.f};
      acc[rt][ct] = z;
    }
#pragma unroll
  for (int kt = 0; kt < 4; kt++) {
    int k = kt * 32 + quad * 8;
    bf16x8 a[4], b[4];
#pragma unroll
    for (int rt = 0; rt < 4; rt++) a[rt] = *(const bf16x8*)(&U[swz(r0 + rt * 16 + l16, k)]);
#pragma unroll
    for (int ct = 0; ct < 4; ct++) b[ct] = *(const bf16x8*)(&V[swz(c0 + ct * 16 + l16, k)]);
#pragma unroll
    for (int rt = 0; rt < 4; rt++)
#pragma unroll
      for (int ct = 0; ct < 4; ct++)
        acc[rt][ct] = __builtin_amdgcn_mfma_f32_16x16x32_bf16(a[rt], b[ct], acc[rt][ct], 0, 0, 0);
  }
}

// store (scale*D + cdiag*I)^T row-major, packed b64 per tile
__device__ __forceinline__ void store_T(ushort_t* dst, const f32x4 (&acc)[4][4],
                                        int r0, int c0, int quad, int l16,
                                        float scale, float cdiag) {
#pragma unroll
  for (int rt = 0; rt < 4; rt++)
#pragma unroll
    for (int ct = 0; ct < 4; ct++) {
      int dr = r0 + rt * 16 + quad * 4, dc = c0 + ct * 16 + l16;
      float v[4];
#pragma unroll
      for (int i = 0; i < 4; i++) {
        v[i] = scale * acc[rt][ct][i];
        if (dr + i == dc) v[i] += cdiag;
      }
      uint2 pk;
      pk.x = (uint_t)f32_bf16(v[0]) | ((uint_t)f32_bf16(v[1]) << 16);
      pk.y = (uint_t)f32_bf16(v[2]) | ((uint_t)f32_bf16(v[3]) << 16);
      *(uint2*)(&dst[swz(dc, dr)]) = pk;
    }
}

__device__ __forceinline__ void set_ident(ushort_t* dst, int t, float c) {
  ushort_t cb = f32_bf16(c);
  for (int i = 0; i < 64; i++) {
    int e = i * 256 + t;
    int r = e >> 7, k = e & 127;
    dst[swz(r, k)] = (r == k) ? cb : (ushort_t)0;
  }
}

// ---------------------------------------------------------------- expm part 1
// block = 2*kmat + which. X=(p-p^T)/8 (s=3 scaling). Y=X^2 symmetric. Z=Y^2.
// Estrin: f(Y) = sum_{i=0..4} Z^i (c_{2i} I + c_{2i+1} Y), Horner in Z.
// Serial matmuls: Y + Z + 4 = 6. All iterates poly(Y): symmetric, commute.
__global__ __launch_bounds__(256, 1) void expm1_kernel(const float* __restrict__ prim,
                                                       ushort_t* __restrict__ wsCS) {
  __shared__ ushort_t __align__(16) bufA[MSZ];  // X -> W (Horner accumulator)
  __shared__ ushort_t __align__(16) bufB[MSZ];  // Y -> Z (in place)
  int kmat = blockIdx.x >> 1, which = blockIdx.x & 1;
  int t = threadIdx.x, wave = t >> 6, lane = t & 63;
  int quad = lane >> 4, l16 = lane & 15;
  int r0 = (wave >> 1) * 64, c0 = (wave & 1) * 64;
  const float* p = prim + kmat * MSZ;

  // stage X -> bufA
  for (int i = 0; i < 64; i++) {
    int e = i * 256 + t;
    int r = e >> 7, c = e & 127;
    bufA[swz(r, c)] = f32_bf16((p[r * 128 + c] - p[c * 128 + r]) * 0.125f);
  }
  __syncthreads();

  f32x4 acc[4][4];
  // Y = X^2 = -(X * X^T) -> bufB (symmetric)
  mm_frag(bufA, bufA, r0, c0, quad, l16, acc);
  __syncthreads();
  store_T(bufB, acc, r0, c0, quad, l16, -1.f, 0.f);
  __syncthreads();

  // cache Y addend fragments in registers: yv[rt][ct] = Y[dc][dr..dr+3]
  uint2 yv[4][4];
#pragma unroll
  for (int rt = 0; rt < 4; rt++)
#pragma unroll
    for (int ct = 0; ct < 4; ct++) {
      int dr = r0 + rt * 16 + quad * 4, dc = c0 + ct * 16 + l16;
      yv[rt][ct] = *(const uint2*)(&bufB[swz(dc, dr)]);
    }

  // Z = Y^2 -> bufB in place (all reads drained at the barrier before store)
  mm_frag(bufB, bufB, r0, c0, quad, l16, acc);
  __syncthreads();
  store_T(bufB, acc, r0, c0, quad, l16, 1.f, 0.f);

  float coef[9];
  if (which == 0) {  // C: c_j = 1/(2j)!
    coef[0] = 1.f; coef[1] = 1.f / 2; coef[2] = 1.f / 24; coef[3] = 1.f / 720;
    coef[4] = 1.f / 40320; coef[5] = 1.f / 3628800.f; coef[6] = 1.f / 479001600.f;
    coef[7] = 1.f / 87178291200.f; coef[8] = 1.f / 20922789888000.f;
  } else {           // S: c_j = 1/(2j+1)!
    coef[0] = 1.f; coef[1] = 1.f / 6; coef[2] = 1.f / 120; coef[3] = 1.f / 5040;
    coef[4] = 1.f / 362880.f; coef[5] = 1.f / 39916800.f; coef[6] = 1.f / 6227020800.f;
    coef[7] = 1.f / 1307674368000.f; coef[8] = 1.f / 355687428096000.f;
  }

  // W = c8*I (bufA; X is dead). Single barrier covers Z-store + ident-store.
  set_ident(bufA, t, coef[8]);
  __syncthreads();

#pragma unroll
  for (int k = 3; k >= 0; k--) {
    mm_frag(bufB, bufA, r0, c0, quad, l16, acc);  // Z * W
    __syncthreads();
    float cd = coef[2 * k], cy = coef[2 * k + 1];
#pragma unroll
    for (int rt = 0; rt < 4; rt++)
#pragma unroll
      for (int ct = 0; ct < 4; ct++) {
        int dr = r0 + rt * 16 + quad * 4, dc = c0 + ct * 16 + l16;
        uint2 yp = yv[rt][ct];
        float y[4] = {bf16_f32((ushort_t)(yp.x & 0xffff)), bf16_f32((ushort_t)(yp.x >> 16)),
                      bf16_f32((ushort_t)(yp.y & 0xffff)), bf16_f32((ushort_t)(yp.y >> 16))};
        float v[4];
#pragma unroll
        for (int i = 0; i < 4; i++) {
          v[i] = acc[rt][ct][i] + cy * y[i];
          if (dr + i == dc) v[i] += cd;
        }
        uint2 pk;
        pk.x = (uint_t)f32_bf16(v[0]) | ((uint_t)f32_bf16(v[1]) << 16);
        pk.y = (uint_t)f32_bf16(v[2]) | ((uint_t)f32_bf16(v[3]) << 16);
        *(uint2*)(&bufA[swz(dc, dr)]) = pk;
      }
    __syncthreads();
  }
  // emit row-major (unswizzled granule copy)
  ushort_t* dst = wsCS + (size_t)(which * NMAT + kmat) * MSZ;
  for (int i = 0; i < 8; i++) {
    int e = (i * 256 + t) * 8;
    int r = e >> 7, k = e & 127;
    *(uint4*)(dst + e) = *(const uint4*)(&bufA[swz(r, k)]);
  }
}

// ---------------------------------------------------------------- expm part 2
// Writes level-1 table entries: TN[b*8+h] = P row-major, TT[b*8+h] = P^T row-major.
__global__ __launch_bounds__(256, 1) void expm2_kernel(
    const float* __restrict__ prim, const ushort_t* __restrict__ wsCS,
    ushort_t* __restrict__ TN, ushort_t* __restrict__ TT) {
  __shared__ ushort_t __align__(16) bufA[MSZ];  // X -> EN/GN (row-major E)
  __shared__ ushort_t __align__(16) bufB[MSZ];  // S -> ET/GT (row-major E^T)
  int kmat = blockIdx.x;
  int t = threadIdx.x, wave = t >> 6, lane = t & 63;
  int quad = lane >> 4, l16 = lane & 15;
  int r0 = (wave >> 1) * 64, c0 = (wave & 1) * 64;
  const float* p = prim + kmat * MSZ;
  const ushort_t* Cg = wsCS + (size_t)kmat * MSZ;
  const ushort_t* Sg = wsCS + (size_t)(NMAT + kmat) * MSZ;

  for (int i = 0; i < 64; i++) {
    int e = i * 256 + t;
    int r = e >> 7, c = e & 127;
    bufA[swz(r, c)] = f32_bf16((p[r * 128 + c] - p[c * 128 + r]) * 0.125f);
  }
  for (int i = 0; i < 8; i++) {
    int e = (i * 256 + t) * 8;
    int r = e >> 7, k = e & 127;
    *(uint4*)(&bufB[swz(r, k)]) = *(const uint4*)(Sg + e);
  }
  __syncthreads();

  f32x4 acc[4][4];
  mm_frag(bufA, bufB, r0, c0, quad, l16, acc);  // F = X * S^T = X*S
  __syncthreads();
#pragma unroll
  for (int rt = 0; rt < 4; rt++)
#pragma unroll
    for (int ct = 0; ct < 4; ct++) {
      int dr = r0 + rt * 16 + quad * 4, dc = c0 + ct * 16 + l16;
      uint2 cp = *(const uint2*)(Cg + dc * 128 + dr);  // C[dc][dr..dr+3]
      float cf[4] = {bf16_f32((ushort_t)(cp.x & 0xffff)), bf16_f32((ushort_t)(cp.x >> 16)),
                     bf16_f32((ushort_t)(cp.y & 0xffff)), bf16_f32((ushort_t)(cp.y >> 16))};
      uint2 en, et;
      en.x = (uint_t)f32_bf16(cf[0] - acc[rt][ct][0]) | ((uint_t)f32_bf16(cf[1] - acc[rt][ct][1]) << 16);
      en.y = (uint_t)f32_bf16(cf[2] - acc[rt][ct][2]) | ((uint_t)f32_bf16(cf[3] - acc[rt][ct][3]) << 16);
      et.x = (uint_t)f32_bf16(cf[0] + acc[rt][ct][0]) | ((uint_t)f32_bf16(cf[1] + acc[rt][ct][1]) << 16);
      et.y = (uint_t)f32_bf16(cf[2] + acc[rt][ct][2]) | ((uint_t)f32_bf16(cf[3] + acc[rt][ct][3]) << 16);
      *(uint2*)(&bufA[swz(dc, dr)]) = en;
      *(uint2*)(&bufB[swz(dc, dr)]) = et;
    }
  __syncthreads();

#pragma unroll 1
  for (int sq = 0; sq < 3; sq++) {
    mm_frag(bufA, bufB, r0, c0, quad, l16, acc);  // G = E*E
    __syncthreads();
#pragma unroll
    for (int rt = 0; rt < 4; rt++)
#pragma unroll
      for (int ct = 0; ct < 4; ct++) {
        int dr = r0 + rt * 16 + quad * 4, dc = c0 + ct * 16 + l16;
        uint2 pk;
        pk.x = (uint_t)f32_bf16(acc[rt][ct][0]) | ((uint_t)f32_bf16(acc[rt][ct][1]) << 16);
        pk.y = (uint_t)f32_bf16(acc[rt][ct][2]) | ((uint_t)f32_bf16(acc[rt][ct][3]) << 16);
        *(uint2*)(&bufB[swz(dc, dr)]) = pk;  // G^T row-major
#pragma unroll
        for (int i = 0; i < 4; i++) bufA[swz(dr + i, dc)] = f32_bf16(acc[rt][ct][i]);  // G row-major
      }
    __syncthreads();
  }
  // emit TN (=P row-major), TT (=P^T row-major) -> table level 1 (off(1)=0)
  for (int i = 0; i < 8; i++) {
    int e = (i * 256 + t) * 8;
    int r = e >> 7, k = e & 127;
    *(uint4*)(TN + (size_t)kmat * MSZ + e) = *(const uint4*)(&bufA[swz(r, k)]);
    *(uint4*)(TT + (size_t)kmat * MSZ + e) = *(const uint4*)(&bufB[swz(r, k)]);
  }
}

// ---------------------------------------------------------------- chunk tables
// T_L[c] = product of P over the L path-bits of c (MSB = root-side step).
// Entry eO = A(prefix) * B(suffix): a-frags from TN[eA] rows, b-frags from
// TT[eB] rows -> D = A * B. Writes TN[eO] (row-major) and TT[eO] (transposed).
// mode 0 (32 blocks):  T2[c] = T1[c>>1] * T1[c&1]
// mode 1 (192 blocks): bx<64:  T3[c] = T2[c>>1] * T1[c&1]
//                      bx>=64: T4[c] = T2[c>>2] * T2[c&3]
__global__ __launch_bounds__(256) void table_kernel(ushort_t* __restrict__ TN,
                                                    ushort_t* __restrict__ TT, int mode) {
  int bx = blockIdx.x;
  int eA, eB, eO, h;
  if (mode == 0) {
    int c = bx >> 3; h = bx & 7;
    eA = c >> 1; eB = c & 1; eO = 2 + c;
  } else {
    if (bx < 64) {
      int c = bx >> 3; h = bx & 7;
      eA = 2 + (c >> 1); eB = c & 1; eO = 6 + c;
    } else {
      int c = (bx - 64) >> 3; h = (bx - 64) & 7;
      eA = 2 + (c >> 2); eB = 2 + (c & 3); eO = 14 + c;
    }
  }
  int t = threadIdx.x, wave = t >> 6, lane = t & 63;
  int quad = lane >> 4, l16 = lane & 15;
  int r0 = (wave >> 1) * 64, c0 = (wave & 1) * 64;
  const ushort_t* A = TN + ((size_t)eA * 8 + h) * MSZ;
  const ushort_t* B = TT + ((size_t)eB * 8 + h) * MSZ;
  ushort_t* oN = TN + ((size_t)eO * 8 + h) * MSZ;
  ushort_t* oT = TT + ((size_t)eO * 8 + h) * MSZ;

  bf16x8 a[4][4], b[4][4];
#pragma unroll
  for (int kt = 0; kt < 4; kt++) {
#pragma unroll
    for (int rt = 0; rt < 4; rt++)
      a[kt][rt] = *(const bf16x8*)(A + (r0 + rt * 16 + l16) * 128 + kt * 32 + quad * 8);
#pragma unroll
    for (int ct = 0; ct < 4; ct++)
      b[kt][ct] = *(const bf16x8*)(B + (c0 + ct * 16 + l16) * 128 + kt * 32 + quad * 8);
  }
  f32x4 acc[4][4];
#pragma unroll
  for (int rt = 0; rt < 4; rt++)
#pragma unroll
    for (int ct = 0; ct < 4; ct++) {
      f32x4 z = {0.f, 0.f, 0.f, 0.f};
      acc[rt][ct] = z;
    }
#pragma unroll
  for (int kt = 0; kt < 4; kt++)
#pragma unroll
    for (int rt = 0; rt < 4; rt++)
#pragma unroll
      for (int ct = 0; ct < 4; ct++)
        acc[rt][ct] = __builtin_amdgcn_mfma_f32_16x16x32_bf16(a[kt][rt], b[kt][ct], acc[rt][ct], 0, 0, 0);
#pragma unroll
  for (int rt = 0; rt < 4; rt++)
#pragma unroll
    for (int ct = 0; ct < 4; ct++) {
      int dr = r0 + rt * 16 + quad * 4, dc = c0 + ct * 16 + l16;
      uint2 pk;
      pk.x = (uint_t)f32_bf16(acc[rt][ct][0]) | ((uint_t)f32_bf16(acc[rt][ct][1]) << 16);
      pk.y = (uint_t)f32_bf16(acc[rt][ct][2]) | ((uint_t)f32_bf16(acc[rt][ct][3]) << 16);
      *(uint2*)(oT + dc * 128 + dr) = pk;  // T^T[dc][dr..dr+3]
#pragma unroll
      for (int i = 0; i < 4; i++) oN[(dr + i) * 128 + dc] = f32_bf16(acc[rt][ct][i]);
    }
}

// ---------------------------------------------------------------- steps
__global__ void steps_kernel(const int* __restrict__ pos, float* __restrict__ os, int N) {
  int i = blockIdx.x, j = threadIdx.x;
  int mi = pos[i] + 1, mj = pos[j] + 1;
  int di = 31 - __builtin_clz((unsigned)mi);
  int dj = 31 - __builtin_clz((unsigned)mj);
  int tt = di < dj ? di : dj;
  unsigned x = (unsigned)((mi >> (di - tt)) ^ (mj >> (dj - tt)));
  int cpl = tt - (x ? (32 - __builtin_clz(x)) : 0);
  os[i * N + j] = (float)(di + dj - 2 * cpl);
}

// ---------------------------------------------------------------- maps (v7)
// Round-1 dataflow (stage first chunk to LDS; per chunk: A-frags gathered from
// global TT, B-frags from swizzled LDS -- never feed MFMA B from global), with
// the occupancy fix: single 32 KB buffer (in-place writeback, barrier-guarded)
// and per-kt A loads so VGPR fits __launch_bounds__(256,4) -> 4 blocks/CU
// (was: 64 KB dbuf, 2 blocks/CU).
__global__ __launch_bounds__(256, 4) void maps_kernel(
    const ushort_t* __restrict__ TN, const ushort_t* __restrict__ TT,
    const int* __restrict__ positions, float* __restrict__ out) {
  __shared__ ushort_t __align__(16) Mb[MSZ];  // 32 KB
  int bx = blockIdx.x;
  int n = bx >> 3, h = bx & 7;
  int t = threadIdx.x, wave = t >> 6, lane = t & 63;
  int quad = lane >> 4, l16 = lane & 15;
  int m = positions[n] + 1;
  int depth = 31 - __builtin_clz((unsigned)m);
  float* ob = out + (size_t)(n * 8 + h) * MSZ;

  if (depth == 0) {
    for (int i = 0; i < 64; i++) {
      int e = i * 256 + t;
      int r = e >> 7, k = e & 127;
      ob[e] = (r == k) ? 1.0f : 0.0f;
    }
    return;
  }
  if (depth <= 4) {  // whole path is one table entry: bf16 -> f32 copy
    int c = m & ((1 << depth) - 1);
    const ushort_t* src = TN + ((size_t)(tab_off(depth) + c) * 8 + h) * MSZ;
    for (int i = 0; i < 8; i++) {
      int e = (i * 256 + t) * 8;
      bf16x8 v = *(const bf16x8*)(src + e);
      f32x4 lo = {bf16_f32((ushort_t)v[0]), bf16_f32((ushort_t)v[1]),
                  bf16_f32((ushort_t)v[2]), bf16_f32((ushort_t)v[3])};
      f32x4 hi = {bf16_f32((ushort_t)v[4]), bf16_f32((ushort_t)v[5]),
                  bf16_f32((ushort_t)v[6]), bf16_f32((ushort_t)v[7])};
      *(f32x4*)(ob + e) = lo;
      *(f32x4*)(ob + e + 4) = hi;
    }
    return;
  }

  int K = (depth + 3) >> 2;           // chunk count (2 or 3 here)
  int L0 = depth - 4 * (K - 1);       // first (root-side) chunk length, 1..4
  int c0v = (m >> (depth - L0)) & ((1 << L0) - 1);
  const ushort_t* src0 = TN + ((size_t)(tab_off(L0) + c0v) * 8 + h) * MSZ;

  int r0 = (wave >> 1) * 64, c0 = (wave & 1) * 64;
  // stage M = first chunk (row-major -> swizzled LDS)
#pragma unroll
  for (int i = 0; i < 8; i++) {
    int e = (i * 256 + t) * 8;
    int r = e >> 7, k = e & 127;
    *(uint4*)(&Mb[swz(r, k)]) = *(const uint4*)(src0 + e);
  }
  __syncthreads();

  int rem = depth - L0;  // multiple of 4
  while (rem > 0) {
    int cb = (m >> (rem - 4)) & 15;
    const ushort_t* Ap = TT + ((size_t)(14 + cb) * 8 + h) * MSZ;
    f32x4 acc[4][4];
#pragma unroll
    for (int rt = 0; rt < 4; rt++)
#pragma unroll
      for (int ct = 0; ct < 4; ct++) {
        f32x4 z = {0.f, 0.f, 0.f, 0.f};
        acc[rt][ct] = z;
      }
#pragma unroll
    for (int kt = 0; kt < 4; kt++) {
      int k = kt * 32 + quad * 8;
      bf16x8 a[4], b[4];  // per-kt A loads keep VGPR under the (256,4) cap
#pragma unroll
      for (int rt = 0; rt < 4; rt++)
        a[rt] = *(const bf16x8*)(Ap + (r0 + rt * 16 + l16) * 128 + k);
#pragma unroll
      for (int ct = 0; ct < 4; ct++) b[ct] = *(const bf16x8*)(&Mb[swz(c0 + ct * 16 + l16, k)]);
#pragma unroll
      for (int rt = 0; rt < 4; rt++)
#pragma unroll
        for (int ct = 0; ct < 4; ct++)
          acc[rt][ct] = __builtin_amdgcn_mfma_f32_16x16x32_bf16(a[rt], b[ct], acc[rt][ct], 0, 0, 0);
    }
    rem -= 4;
    if (rem == 0) {
      // D = (M*T)^T: lane holds D[dr..+3][dc] = M_next[dc][dr..+3] -> float4 rows
#pragma unroll
      for (int rt = 0; rt < 4; rt++)
#pragma unroll
        for (int ct = 0; ct < 4; ct++) {
          int dr = r0 + rt * 16 + quad * 4;
          int dc = c0 + ct * 16 + l16;
          *(f32x4*)(ob + dc * 128 + dr) = acc[rt][ct];
        }
    } else {
      __syncthreads();  // all waves done reading Mb before in-place overwrite
#pragma unroll
      for (int rt = 0; rt < 4; rt++)
#pragma unroll
        for (int ct = 0; ct < 4; ct++) {
          int dr = r0 + rt * 16 + quad * 4;
          int dc = c0 + ct * 16 + l16;
          uint2 pk;
          pk.x = (uint_t)f32_bf16(acc[rt][ct][0]) | ((uint_t)f32_bf16(acc[rt][ct][1]) << 16);
          pk.y = (uint_t)f32_bf16(acc[rt][ct][2]) | ((uint_t)f32_bf16(acc[rt][ct][3]) << 16);
          *(uint2*)(&Mb[swz(dc, dr)]) = pk;
        }
      __syncthreads();
    }
  }
}

// ---------------------------------------------------------------- launch
extern "C" void kernel_launch(void* const* d_in, const int* in_sizes, int n_in,
                              void* d_out, int out_size, void* d_ws, size_t ws_size,
                              hipStream_t stream) {
  const float* prim = (const float*)d_in[0];
  const int* positions = (const int*)d_in[1];
  int N = in_sizes[1];  // 256
  float* out = (float*)d_out;

  // workspace: wsCS 32 mats | TN 30*8 mats | TT 30*8 mats  => 16 MB total
  ushort_t* wsCS = (ushort_t*)d_ws;
  ushort_t* TN = wsCS + (size_t)2 * NMAT * MSZ;
  ushort_t* TT = TN + (size_t)NTAB * 8 * MSZ;

  steps_kernel<<<N, N, 0, stream>>>(positions, out + (size_t)N * 8 * MSZ, N);
  expm1_kernel<<<2 * NMAT, 256, 0, stream>>>(prim, wsCS);
  expm2_kernel<<<NMAT, 256, 0, stream>>>(prim, wsCS, TN, TT);  // level 1
  table_kernel<<<32, 256, 0, stream>>>(TN, TT, 0);             // level 2
  table_kernel<<<192, 256, 0, stream>>>(TN, TT, 1);            // levels 3,4
  maps_kernel<<<N * 8, 256, 0, stream>>>(TN, TT, positions, out);
}

// Round 8
// 221.035 us; speedup vs baseline: 1.2224x; 1.0641x over previous
//
#include <hip/hip_runtime.h>

typedef unsigned short ushort_t;
typedef unsigned int uint_t;
typedef __attribute__((ext_vector_type(8))) short bf16x8;
typedef __attribute__((ext_vector_type(4))) float f32x4;

#define NMAT 16
#define MSZ 16384  // 128*128
#define NTAB 30    // table entries: levels 1..4, off(L) = {0,2,6,14}

__device__ __forceinline__ ushort_t f32_bf16(float f) {
  uint_t u = __builtin_bit_cast(uint_t, f);
  u += 0x7FFFu + ((u >> 16) & 1u);  // round-to-nearest-even
  return (ushort_t)(u >> 16);
}

__device__ __forceinline__ float bf16_f32(ushort_t b) {
  uint_t u = ((uint_t)b) << 16;
  return __builtin_bit_cast(float, u);
}

// XOR swizzle on 16B granules: row r, elem k of a 128x128 bf16 tile.
__device__ __forceinline__ int swz(int r, int k) {
  return r * 128 + (((k >> 3) ^ (r & 7)) << 3) + (k & 7);
}

// level-L chunks live at [off(L) .. off(L)+2^L)
__device__ __forceinline__ int tab_off(int L) {
  return (L == 1) ? 0 : (L == 2) ? 2 : (L == 3) ? 6 : 14;  // 30 entries total
}

// D[r][c] = sum_k U[r][k]*V[c][k] = U * V^T (U,V swizzled LDS tiles).
__device__ __forceinline__ void mm_frag(const ushort_t* U, const ushort_t* V,
                                        int r0, int c0, int quad, int l16,
                                        f32x4 (&acc)[4][4]) {
#pragma unroll
  for (int rt = 0; rt < 4; rt++)
#pragma unroll
    for (int ct = 0; ct < 4; ct++) {
      f32x4 z = {0.f, 0.f, 0.f, 0.f};
      acc[rt][ct] = z;
    }
#pragma unroll
  for (int kt = 0; kt < 4; kt++) {
    int k = kt * 32 + quad * 8;
    bf16x8 a[4], b[4];
#pragma unroll
    for (int rt = 0; rt < 4; rt++) a[rt] = *(const bf16x8*)(&U[swz(r0 + rt * 16 + l16, k)]);
#pragma unroll
    for (int ct = 0; ct < 4; ct++) b[ct] = *(const bf16x8*)(&V[swz(c0 + ct * 16 + l16, k)]);
#pragma unroll
    for (int rt = 0; rt < 4; rt++)
#pragma unroll
      for (int ct = 0; ct < 4; ct++)
        acc[rt][ct] = __builtin_amdgcn_mfma_f32_16x16x32_bf16(a[rt], b[ct], acc[rt][ct], 0, 0, 0);
  }
}

// store (scale*D + cdiag*I)^T row-major, packed b64 per tile
__device__ __forceinline__ void store_T(ushort_t* dst, const f32x4 (&acc)[4][4],
                                        int r0, int c0, int quad, int l16,
                                        float scale, float cdiag) {
#pragma unroll
  for (int rt = 0; rt < 4; rt++)
#pragma unroll
    for (int ct = 0; ct < 4; ct++) {
      int dr = r0 + rt * 16 + quad * 4, dc = c0 + ct * 16 + l16;
      float v[4];
#pragma unroll
      for (int i = 0; i < 4; i++) {
        v[i] = scale * acc[rt][ct][i];
        if (dr + i == dc) v[i] += cdiag;
      }
      uint2 pk;
      pk.x = (uint_t)f32_bf16(v[0]) | ((uint_t)f32_bf16(v[1]) << 16);
      pk.y = (uint_t)f32_bf16(v[2]) | ((uint_t)f32_bf16(v[3]) << 16);
      *(uint2*)(&dst[swz(dc, dr)]) = pk;
    }
}

__device__ __forceinline__ void set_ident(ushort_t* dst, int t, float c) {
  ushort_t cb = f32_bf16(c);
  for (int i = 0; i < 64; i++) {
    int e = i * 256 + t;
    int r = e >> 7, k = e & 127;
    dst[swz(r, k)] = (r == k) ? cb : (ushort_t)0;
  }
}

// ---------------------------------------------------------------- expm part 1
// block = 2*kmat + which. X=(p-p^T)/8 (s=3 scaling). Y=X^2 symmetric. Z=Y^2.
// Estrin: f(Y) = sum_{i=0..4} Z^i (c_{2i} I + c_{2i+1} Y), Horner in Z.
// Serial matmuls: Y + Z + 4 = 6. All iterates poly(Y): symmetric, commute.
__global__ __launch_bounds__(256, 1) void expm1_kernel(const float* __restrict__ prim,
                                                       ushort_t* __restrict__ wsCS) {
  __shared__ ushort_t __align__(16) bufA[MSZ];  // X -> W (Horner accumulator)
  __shared__ ushort_t __align__(16) bufB[MSZ];  // Y -> Z (in place)
  int kmat = blockIdx.x >> 1, which = blockIdx.x & 1;
  int t = threadIdx.x, wave = t >> 6, lane = t & 63;
  int quad = lane >> 4, l16 = lane & 15;
  int r0 = (wave >> 1) * 64, c0 = (wave & 1) * 64;
  const float* p = prim + kmat * MSZ;

  // stage X -> bufA
  for (int i = 0; i < 64; i++) {
    int e = i * 256 + t;
    int r = e >> 7, c = e & 127;
    bufA[swz(r, c)] = f32_bf16((p[r * 128 + c] - p[c * 128 + r]) * 0.125f);
  }
  __syncthreads();

  f32x4 acc[4][4];
  // Y = X^2 = -(X * X^T) -> bufB (symmetric)
  mm_frag(bufA, bufA, r0, c0, quad, l16, acc);
  __syncthreads();
  store_T(bufB, acc, r0, c0, quad, l16, -1.f, 0.f);
  __syncthreads();

  // cache Y addend fragments in registers: yv[rt][ct] = Y[dc][dr..dr+3]
  uint2 yv[4][4];
#pragma unroll
  for (int rt = 0; rt < 4; rt++)
#pragma unroll
    for (int ct = 0; ct < 4; ct++) {
      int dr = r0 + rt * 16 + quad * 4, dc = c0 + ct * 16 + l16;
      yv[rt][ct] = *(const uint2*)(&bufB[swz(dc, dr)]);
    }

  // Z = Y^2 -> bufB in place (all reads drained at the barrier before store)
  mm_frag(bufB, bufB, r0, c0, quad, l16, acc);
  __syncthreads();
  store_T(bufB, acc, r0, c0, quad, l16, 1.f, 0.f);

  float coef[9];
  if (which == 0) {  // C: c_j = 1/(2j)!
    coef[0] = 1.f; coef[1] = 1.f / 2; coef[2] = 1.f / 24; coef[3] = 1.f / 720;
    coef[4] = 1.f / 40320; coef[5] = 1.f / 3628800.f; coef[6] = 1.f / 479001600.f;
    coef[7] = 1.f / 87178291200.f; coef[8] = 1.f / 20922789888000.f;
  } else {           // S: c_j = 1/(2j+1)!
    coef[0] = 1.f; coef[1] = 1.f / 6; coef[2] = 1.f / 120; coef[3] = 1.f / 5040;
    coef[4] = 1.f / 362880.f; coef[5] = 1.f / 39916800.f; coef[6] = 1.f / 6227020800.f;
    coef[7] = 1.f / 1307674368000.f; coef[8] = 1.f / 355687428096000.f;
  }

  // W = c8*I (bufA; X is dead). Single barrier covers Z-store + ident-store.
  set_ident(bufA, t, coef[8]);
  __syncthreads();

#pragma unroll
  for (int k = 3; k >= 0; k--) {
    mm_frag(bufB, bufA, r0, c0, quad, l16, acc);  // Z * W
    __syncthreads();
    float cd = coef[2 * k], cy = coef[2 * k + 1];
#pragma unroll
    for (int rt = 0; rt < 4; rt++)
#pragma unroll
      for (int ct = 0; ct < 4; ct++) {
        int dr = r0 + rt * 16 + quad * 4, dc = c0 + ct * 16 + l16;
        uint2 yp = yv[rt][ct];
        float y[4] = {bf16_f32((ushort_t)(yp.x & 0xffff)), bf16_f32((ushort_t)(yp.x >> 16)),
                      bf16_f32((ushort_t)(yp.y & 0xffff)), bf16_f32((ushort_t)(yp.y >> 16))};
        float v[4];
#pragma unroll
        for (int i = 0; i < 4; i++) {
          v[i] = acc[rt][ct][i] + cy * y[i];
          if (dr + i == dc) v[i] += cd;
        }
        uint2 pk;
        pk.x = (uint_t)f32_bf16(v[0]) | ((uint_t)f32_bf16(v[1]) << 16);
        pk.y = (uint_t)f32_bf16(v[2]) | ((uint_t)f32_bf16(v[3]) << 16);
        *(uint2*)(&bufA[swz(dc, dr)]) = pk;
      }
    __syncthreads();
  }
  // emit row-major (unswizzled granule copy)
  ushort_t* dst = wsCS + (size_t)(which * NMAT + kmat) * MSZ;
  for (int i = 0; i < 8; i++) {
    int e = (i * 256 + t) * 8;
    int r = e >> 7, k = e & 127;
    *(uint4*)(dst + e) = *(const uint4*)(&bufA[swz(r, k)]);
  }
}

// ---------------------------------------------------------------- expm part 2
// Writes level-1 table entries: TN[b*8+h] = P row-major, TT[b*8+h] = P^T row-major.
__global__ __launch_bounds__(256, 1) void expm2_kernel(
    const float* __restrict__ prim, const ushort_t* __restrict__ wsCS,
    ushort_t* __restrict__ TN, ushort_t* __restrict__ TT) {
  __shared__ ushort_t __align__(16) bufA[MSZ];  // X -> EN/GN (row-major E)
  __shared__ ushort_t __align__(16) bufB[MSZ];  // S -> ET/GT (row-major E^T)
  int kmat = blockIdx.x;
  int t = threadIdx.x, wave = t >> 6, lane = t & 63;
  int quad = lane >> 4, l16 = lane & 15;
  int r0 = (wave >> 1) * 64, c0 = (wave & 1) * 64;
  const float* p = prim + kmat * MSZ;
  const ushort_t* Cg = wsCS + (size_t)kmat * MSZ;
  const ushort_t* Sg = wsCS + (size_t)(NMAT + kmat) * MSZ;

  for (int i = 0; i < 64; i++) {
    int e = i * 256 + t;
    int r = e >> 7, c = e & 127;
    bufA[swz(r, c)] = f32_bf16((p[r * 128 + c] - p[c * 128 + r]) * 0.125f);
  }
  for (int i = 0; i < 8; i++) {
    int e = (i * 256 + t) * 8;
    int r = e >> 7, k = e & 127;
    *(uint4*)(&bufB[swz(r, k)]) = *(const uint4*)(Sg + e);
  }
  __syncthreads();

  f32x4 acc[4][4];
  mm_frag(bufA, bufB, r0, c0, quad, l16, acc);  // F = X * S^T = X*S
  __syncthreads();
#pragma unroll
  for (int rt = 0; rt < 4; rt++)
#pragma unroll
    for (int ct = 0; ct < 4; ct++) {
      int dr = r0 + rt * 16 + quad * 4, dc = c0 + ct * 16 + l16;
      uint2 cp = *(const uint2*)(Cg + dc * 128 + dr);  // C[dc][dr..dr+3]
      float cf[4] = {bf16_f32((ushort_t)(cp.x & 0xffff)), bf16_f32((ushort_t)(cp.x >> 16)),
                     bf16_f32((ushort_t)(cp.y & 0xffff)), bf16_f32((ushort_t)(cp.y >> 16))};
      uint2 en, et;
      en.x = (uint_t)f32_bf16(cf[0] - acc[rt][ct][0]) | ((uint_t)f32_bf16(cf[1] - acc[rt][ct][1]) << 16);
      en.y = (uint_t)f32_bf16(cf[2] - acc[rt][ct][2]) | ((uint_t)f32_bf16(cf[3] - acc[rt][ct][3]) << 16);
      et.x = (uint_t)f32_bf16(cf[0] + acc[rt][ct][0]) | ((uint_t)f32_bf16(cf[1] + acc[rt][ct][1]) << 16);
      et.y = (uint_t)f32_bf16(cf[2] + acc[rt][ct][2]) | ((uint_t)f32_bf16(cf[3] + acc[rt][ct][3]) << 16);
      *(uint2*)(&bufA[swz(dc, dr)]) = en;
      *(uint2*)(&bufB[swz(dc, dr)]) = et;
    }
  __syncthreads();

#pragma unroll 1
  for (int sq = 0; sq < 3; sq++) {
    mm_frag(bufA, bufB, r0, c0, quad, l16, acc);  // G = E*E
    __syncthreads();
#pragma unroll
    for (int rt = 0; rt < 4; rt++)
#pragma unroll
      for (int ct = 0; ct < 4; ct++) {
        int dr = r0 + rt * 16 + quad * 4, dc = c0 + ct * 16 + l16;
        uint2 pk;
        pk.x = (uint_t)f32_bf16(acc[rt][ct][0]) | ((uint_t)f32_bf16(acc[rt][ct][1]) << 16);
        pk.y = (uint_t)f32_bf16(acc[rt][ct][2]) | ((uint_t)f32_bf16(acc[rt][ct][3]) << 16);
        *(uint2*)(&bufB[swz(dc, dr)]) = pk;  // G^T row-major
#pragma unroll
        for (int i = 0; i < 4; i++) bufA[swz(dr + i, dc)] = f32_bf16(acc[rt][ct][i]);  // G row-major
      }
    __syncthreads();
  }
  // emit TN (=P row-major), TT (=P^T row-major) -> table level 1 (off(1)=0)
  for (int i = 0; i < 8; i++) {
    int e = (i * 256 + t) * 8;
    int r = e >> 7, k = e & 127;
    *(uint4*)(TN + (size_t)kmat * MSZ + e) = *(const uint4*)(&bufA[swz(r, k)]);
    *(uint4*)(TT + (size_t)kmat * MSZ + e) = *(const uint4*)(&bufB[swz(r, k)]);
  }
}

// ---------------------------------------------------------------- chunk tables
// T_L[c] = product of P over the L path-bits of c (MSB = root-side step).
// Entry eO = A(prefix) * B(suffix): a-frags from TN[eA] rows, b-frags from
// TT[eB] rows -> D = A * B. Writes TN[eO] (row-major) and TT[eO] (transposed).
// mode 0 (32 blocks):  T2[c] = T1[c>>1] * T1[c&1]
// mode 1 (192 blocks): bx<64:  T3[c] = T2[c>>1] * T1[c&1]
//                      bx>=64: T4[c] = T2[c>>2] * T2[c&3]
__global__ __launch_bounds__(256) void table_kernel(ushort_t* __restrict__ TN,
                                                    ushort_t* __restrict__ TT, int mode) {
  int bx = blockIdx.x;
  int eA, eB, eO, h;
  if (mode == 0) {
    int c = bx >> 3; h = bx & 7;
    eA = c >> 1; eB = c & 1; eO = 2 + c;
  } else {
    if (bx < 64) {
      int c = bx >> 3; h = bx & 7;
      eA = 2 + (c >> 1); eB = c & 1; eO = 6 + c;
    } else {
      int c = (bx - 64) >> 3; h = (bx - 64) & 7;
      eA = 2 + (c >> 2); eB = 2 + (c & 3); eO = 14 + c;
    }
  }
  int t = threadIdx.x, wave = t >> 6, lane = t & 63;
  int quad = lane >> 4, l16 = lane & 15;
  int r0 = (wave >> 1) * 64, c0 = (wave & 1) * 64;
  const ushort_t* A = TN + ((size_t)eA * 8 + h) * MSZ;
  const ushort_t* B = TT + ((size_t)eB * 8 + h) * MSZ;
  ushort_t* oN = TN + ((size_t)eO * 8 + h) * MSZ;
  ushort_t* oT = TT + ((size_t)eO * 8 + h) * MSZ;

  bf16x8 a[4][4], b[4][4];
#pragma unroll
  for (int kt = 0; kt < 4; kt++) {
#pragma unroll
    for (int rt = 0; rt < 4; rt++)
      a[kt][rt] = *(const bf16x8*)(A + (r0 + rt * 16 + l16) * 128 + kt * 32 + quad * 8);
#pragma unroll
    for (int ct = 0; ct < 4; ct++)
      b[kt][ct] = *(const bf16x8*)(B + (c0 + ct * 16 + l16) * 128 + kt * 32 + quad * 8);
  }
  f32x4 acc[4][4];
#pragma unroll
  for (int rt = 0; rt < 4; rt++)
#pragma unroll
    for (int ct = 0; ct < 4; ct++) {
      f32x4 z = {0.f, 0.f, 0.f, 0.f};
      acc[rt][ct] = z;
    }
#pragma unroll
  for (int kt = 0; kt < 4; kt++)
#pragma unroll
    for (int rt = 0; rt < 4; rt++)
#pragma unroll
      for (int ct = 0; ct < 4; ct++)
        acc[rt][ct] = __builtin_amdgcn_mfma_f32_16x16x32_bf16(a[kt][rt], b[kt][ct], acc[rt][ct], 0, 0, 0);
#pragma unroll
  for (int rt = 0; rt < 4; rt++)
#pragma unroll
    for (int ct = 0; ct < 4; ct++) {
      int dr = r0 + rt * 16 + quad * 4, dc = c0 + ct * 16 + l16;
      uint2 pk;
      pk.x = (uint_t)f32_bf16(acc[rt][ct][0]) | ((uint_t)f32_bf16(acc[rt][ct][1]) << 16);
      pk.y = (uint_t)f32_bf16(acc[rt][ct][2]) | ((uint_t)f32_bf16(acc[rt][ct][3]) << 16);
      *(uint2*)(oT + dc * 128 + dr) = pk;  // T^T[dc][dr..dr+3]
#pragma unroll
      for (int i = 0; i < 4; i++) oN[(dr + i) * 128 + dc] = f32_bf16(acc[rt][ct][i]);
    }
}

// ---------------------------------------------------------------- steps
__global__ void steps_kernel(const int* __restrict__ pos, float* __restrict__ os, int N) {
  int i = blockIdx.x, j = threadIdx.x;
  int mi = pos[i] + 1, mj = pos[j] + 1;
  int di = 31 - __builtin_clz((unsigned)mi);
  int dj = 31 - __builtin_clz((unsigned)mj);
  int tt = di < dj ? di : dj;
  unsigned x = (unsigned)((mi >> (di - tt)) ^ (mj >> (dj - tt)));
  int cpl = tt - (x ? (32 - __builtin_clz(x)) : 0);
  os[i * N + j] = (float)(di + dj - 2 * cpl);
}

// ---------------------------------------------------------------- maps (v9)
// Round-1 v4 dataflow (the 224 us champion): stage first chunk to LDS dbuf,
// per chunk A-frags preloaded upfront from global TT (16 loads), B-frags from
// swizzled LDS. Deltas vs v4, pure code motion (software pipelining):
//  - A1 preload issued BEFORE the stage barrier (loads stay in flight across it)
//  - A2 preload issued right after step-1 MFMAs (latency hides under
//    writeback + barrier + step-2 b-loads)
// (nontemporal stores removed pending infra diagnosis -- only unverified
//  construct in the r6/r7 source that failed to run)
__global__ __launch_bounds__(256, 2) void maps_kernel(
    const ushort_t* __restrict__ TN, const ushort_t* __restrict__ TT,
    const int* __restrict__ positions, float* __restrict__ out) {
  __shared__ ushort_t __align__(16) Mb[2][MSZ];  // 64 KB
  int bx = blockIdx.x;
  int n = bx >> 3, h = bx & 7;
  int t = threadIdx.x, wave = t >> 6, lane = t & 63;
  int quad = lane >> 4, l16 = lane & 15;
  int m = positions[n] + 1;
  int depth = 31 - __builtin_clz((unsigned)m);
  float* ob = out + (size_t)(n * 8 + h) * MSZ;

  if (depth == 0) {
    for (int i = 0; i < 64; i++) {
      int e = i * 256 + t;
      int r = e >> 7, k = e & 127;
      ob[e] = (r == k) ? 1.0f : 0.0f;
    }
    return;
  }
  if (depth <= 4) {  // whole path is one table entry: bf16 -> f32 copy
    int c = m & ((1 << depth) - 1);
    const ushort_t* src = TN + ((size_t)(tab_off(depth) + c) * 8 + h) * MSZ;
    for (int i = 0; i < 8; i++) {
      int e = (i * 256 + t) * 8;
      bf16x8 v = *(const bf16x8*)(src + e);
      f32x4 lo = {bf16_f32((ushort_t)v[0]), bf16_f32((ushort_t)v[1]),
                  bf16_f32((ushort_t)v[2]), bf16_f32((ushort_t)v[3])};
      f32x4 hi = {bf16_f32((ushort_t)v[4]), bf16_f32((ushort_t)v[5]),
                  bf16_f32((ushort_t)v[6]), bf16_f32((ushort_t)v[7])};
      *(f32x4*)(ob + e) = lo;
      *(f32x4*)(ob + e + 4) = hi;
    }
    return;
  }

  int K = (depth + 3) >> 2;           // 2 or 3 chunks
  int L0 = depth - 4 * (K - 1);       // first (root-side) chunk length, 1..4
  int c0v = (m >> (depth - L0)) & ((1 << L0) - 1);
  const ushort_t* src0 = TN + ((size_t)(tab_off(L0) + c0v) * 8 + h) * MSZ;
  bool two = (K == 3);
  int c1 = (m >> (4 * (K - 2))) & 15;  // first suffix chunk
  int c2 = m & 15;                     // second suffix chunk (K==3 only)
  const ushort_t* Ap1 = TT + ((size_t)(14 + c1) * 8 + h) * MSZ;
  const ushort_t* Ap2 = TT + ((size_t)(14 + c2) * 8 + h) * MSZ;

  int r0 = (wave >> 1) * 64, c0 = (wave & 1) * 64;
  // stage M0 = first chunk (row-major -> swizzled LDS)
#pragma unroll
  for (int i = 0; i < 8; i++) {
    int e = (i * 256 + t) * 8;
    int r = e >> 7, k = e & 127;
    *(uint4*)(&Mb[0][swz(r, k)]) = *(const uint4*)(src0 + e);
  }
  // A1 preload BEFORE the barrier: global loads stay in flight across it
  bf16x8 a1[4][4];
#pragma unroll
  for (int kt = 0; kt < 4; kt++)
#pragma unroll
    for (int rt = 0; rt < 4; rt++)
      a1[kt][rt] = *(const bf16x8*)(Ap1 + (r0 + rt * 16 + l16) * 128 + kt * 32 + quad * 8);
  __syncthreads();

  // step 1: acc = T[c1]^T * M0^T
  f32x4 acc[4][4];
#pragma unroll
  for (int rt = 0; rt < 4; rt++)
#pragma unroll
    for (int ct = 0; ct < 4; ct++) {
      f32x4 z = {0.f, 0.f, 0.f, 0.f};
      acc[rt][ct] = z;
    }
#pragma unroll
  for (int kt = 0; kt < 4; kt++) {
    int k = kt * 32 + quad * 8;
    bf16x8 b[4];
#pragma unroll
    for (int ct = 0; ct < 4; ct++) b[ct] = *(const bf16x8*)(&Mb[0][swz(c0 + ct * 16 + l16, k)]);
#pragma unroll
    for (int rt = 0; rt < 4; rt++)
#pragma unroll
      for (int ct = 0; ct < 4; ct++)
        acc[rt][ct] = __builtin_amdgcn_mfma_f32_16x16x32_bf16(a1[kt][rt], b[ct], acc[rt][ct], 0, 0, 0);
  }

  if (two) {
    // A2 preload now: latency hides under writeback + barrier + step-2 b-loads
    bf16x8 a2[4][4];
#pragma unroll
    for (int kt = 0; kt < 4; kt++)
#pragma unroll
      for (int rt = 0; rt < 4; rt++)
        a2[kt][rt] = *(const bf16x8*)(Ap2 + (r0 + rt * 16 + l16) * 128 + kt * 32 + quad * 8);
    // writeback M1 -> other buffer (packed), one barrier
#pragma unroll
    for (int rt = 0; rt < 4; rt++)
#pragma unroll
      for (int ct = 0; ct < 4; ct++) {
        int dr = r0 + rt * 16 + quad * 4;
        int dc = c0 + ct * 16 + l16;
        uint2 pk;
        pk.x = (uint_t)f32_bf16(acc[rt][ct][0]) | ((uint_t)f32_bf16(acc[rt][ct][1]) << 16);
        pk.y = (uint_t)f32_bf16(acc[rt][ct][2]) | ((uint_t)f32_bf16(acc[rt][ct][3]) << 16);
        *(uint2*)(&Mb[1][swz(dc, dr)]) = pk;
      }
    __syncthreads();

    // step 2: acc = T[c2]^T * M1^T
#pragma unroll
    for (int rt = 0; rt < 4; rt++)
#pragma unroll
      for (int ct = 0; ct < 4; ct++) {
        f32x4 z = {0.f, 0.f, 0.f, 0.f};
        acc[rt][ct] = z;
      }
#pragma unroll
    for (int kt = 0; kt < 4; kt++) {
      int k = kt * 32 + quad * 8;
      bf16x8 b[4];
#pragma unroll
      for (int ct = 0; ct < 4; ct++) b[ct] = *(const bf16x8*)(&Mb[1][swz(c0 + ct * 16 + l16, k)]);
#pragma unroll
      for (int rt = 0; rt < 4; rt++)
#pragma unroll
        for (int ct = 0; ct < 4; ct++)
          acc[rt][ct] = __builtin_amdgcn_mfma_f32_16x16x32_bf16(a2[kt][rt], b[ct], acc[rt][ct], 0, 0, 0);
    }
  }

  // final: lane holds M[dc][dr..dr+3] -> packed f32x4 rows
#pragma unroll
  for (int rt = 0; rt < 4; rt++)
#pragma unroll
    for (int ct = 0; ct < 4; ct++) {
      int dr = r0 + rt * 16 + quad * 4;
      int dc = c0 + ct * 16 + l16;
      *(f32x4*)(ob + dc * 128 + dr) = acc[rt][ct];
    }
}

// ---------------------------------------------------------------- launch
extern "C" void kernel_launch(void* const* d_in, const int* in_sizes, int n_in,
                              void* d_out, int out_size, void* d_ws, size_t ws_size,
                              hipStream_t stream) {
  const float* prim = (const float*)d_in[0];
  const int* positions = (const int*)d_in[1];
  int N = in_sizes[1];  // 256
  float* out = (float*)d_out;

  // workspace: wsCS 32 mats | TN 30*8 mats | TT 30*8 mats  => 16 MB total
  ushort_t* wsCS = (ushort_t*)d_ws;
  ushort_t* TN = wsCS + (size_t)2 * NMAT * MSZ;
  ushort_t* TT = TN + (size_t)NTAB * 8 * MSZ;

  steps_kernel<<<N, N, 0, stream>>>(positions, out + (size_t)N * 8 * MSZ, N);
  expm1_kernel<<<2 * NMAT, 256, 0, stream>>>(prim, wsCS);
  expm2_kernel<<<NMAT, 256, 0, stream>>>(prim, wsCS, TN, TT);  // level 1
  table_kernel<<<32, 256, 0, stream>>>(TN, TT, 0);             // level 2
  table_kernel<<<192, 256, 0, stream>>>(TN, TT, 1);            // levels 3,4
  maps_kernel<<<N * 8, 256, 0, stream>>>(TN, TT, positions, out);
}